// Round 1
// baseline (797.922 us; speedup 1.0000x reference)
//
#include <hip/hip_runtime.h>
#include <math.h>

// Problem constants
static constexpr int BB = 4;        // batch
static constexpr int NN = 16384;    // nodes per batch
static constexpr int KK = 8;        // neighbors per node
static constexpr int EE = 131072;   // edges per batch = NN*KK
static constexpr int RR = 65536;    // BB*NN rows
static constexpr int EG = 524288;   // BB*EE edges total

// Workspace layout (float offsets)
static constexpr size_t OFF_X0 = 0;                      // 65536*32
static constexpr size_t OFF_X1 = OFF_X0 + (size_t)RR*32; // 65536*64
static constexpr size_t OFF_X2 = OFF_X1 + (size_t)RR*64; // 65536*128
static constexpr size_t OFF_X3 = OFF_X2 + (size_t)RR*128;// 65536*256
static constexpr size_t OFF_ZB = OFF_X3 + (size_t)RR*256;// 65536*256 (b-branch scratch)
static constexpr size_t OFF_ZC = OFF_ZB + (size_t)RR*256;// 65536
static constexpr size_t OFF_S  = OFF_ZC + (size_t)RR;    // 9 slots * 512
static constexpr size_t OFF_SS = OFF_S + 9*512;          // 9 slots * 512

__device__ __forceinline__ float lrelu(float x) { return fmaxf(x, 0.2f*x); }

// ---------------- layer 0: node GEMM 8->32 (pre-BN) ----------------
__global__ __launch_bounds__(256) void k_l0_node(const float* __restrict__ xf,
                                                 const float* __restrict__ W,
                                                 float* __restrict__ z) {
    __shared__ float w[256];
    int tid = threadIdx.x;
    w[tid] = W[tid];
    __syncthreads();
    int r = blockIdx.x*256 + tid;
    const float4* xr = (const float4*)(xf + (size_t)r*8);
    float4 a = xr[0], b = xr[1];
    float xv[8] = {a.x,a.y,a.z,a.w,b.x,b.y,b.z,b.w};
    float4 outv[8];
    float* op = (float*)outv;
#pragma unroll
    for (int c = 0; c < 32; ++c) {
        float s = 0.f;
#pragma unroll
        for (int k = 0; k < 8; ++k) s = fmaf(xv[k], w[k*32+c], s);
        op[c] = s;
    }
    float4* zp = (float4*)(z + (size_t)r*32);
#pragma unroll
    for (int i = 0; i < 8; ++i) zp[i] = outv[i];
}

// ---------------- column stats: sum & sumsq per column ----------------
template<int C>
__global__ __launch_bounds__(256) void k_colstats(const float* __restrict__ Z, int R,
                                                  float* __restrict__ S) {
    constexpr int TPC = 256 / C;  // threads per column in a block
    __shared__ float ls[256];
    __shared__ float lq[256];
    int tid = threadIdx.x;
    int c = tid % C, rr = tid / C;
    float s = 0.f, q = 0.f;
    for (int r = blockIdx.x*TPC + rr; r < R; r += gridDim.x*TPC) {
        float v = Z[(size_t)r*C + c];
        s += v; q = fmaf(v, v, q);
    }
    ls[tid] = s; lq[tid] = q;
    __syncthreads();
#pragma unroll
    for (int half = TPC/2; half >= 1; half >>= 1) {
        if (rr < half) { ls[tid] += ls[tid + half*C]; lq[tid] += lq[tid + half*C]; }
        __syncthreads();
    }
    if (rr == 0) { atomicAdd(&S[c], ls[tid]); atomicAdd(&S[C+c], lq[tid]); }
}

// ---------------- finalize: scale/shift from stats ----------------
__global__ void k_finalize(const float* __restrict__ S, const float* __restrict__ g,
                           const float* __restrict__ b, float invR,
                           float* __restrict__ SS, int C) {
    int c = threadIdx.x;
    if (c < C) {
        float m = S[c]*invR;
        float v = fmaxf(S[C+c]*invR - m*m, 0.f);
        float sc = g[c]*rsqrtf(v + 1e-5f);
        SS[c] = sc;
        SS[C+c] = fmaf(-m, sc, b[c]);
    }
}

// ---------------- in-place BN + leaky ----------------
template<int C>
__global__ __launch_bounds__(256) void k_bn_act(float* __restrict__ Z,
                                                const float* __restrict__ SS, int n4) {
    int i = blockIdx.x*256 + threadIdx.x;
    if (i >= n4) return;
    int c0 = (i*4) % C;
    float4 z = ((float4*)Z)[i];
    float4 sc = *(const float4*)&SS[c0];
    float4 sh = *(const float4*)&SS[C+c0];
    z.x = lrelu(fmaf(z.x, sc.x, sh.x));
    z.y = lrelu(fmaf(z.y, sc.y, sh.y));
    z.z = lrelu(fmaf(z.z, sc.z, sh.z));
    z.w = lrelu(fmaf(z.w, sc.w, sh.w));
    ((float4*)Z)[i] = z;
}

// ---------------- layer 0 edge MLP: stats pass ----------------
__global__ __launch_bounds__(256) void k_edge_stats(const float* __restrict__ xf,
                                                    const int* __restrict__ ei,
                                                    const float* __restrict__ W,
                                                    float* __restrict__ S) {
    __shared__ float w[256];
    __shared__ float red[64];
    int tid = threadIdx.x;
    w[tid] = W[tid];
    if (tid < 64) red[tid] = 0.f;
    __syncthreads();
    float s[32], q[32];
#pragma unroll
    for (int c = 0; c < 32; ++c) { s[c] = 0.f; q[c] = 0.f; }
    for (int e = blockIdx.x*256 + tid; e < EG; e += gridDim.x*256) {
        int b = e >> 17, j = e & (EE-1);
        const int* base = ei + (size_t)b*2*EE;
        int ctr = base[j], nbr = base[EE + j];
        const float4* pc = (const float4*)(xf + ((size_t)(b<<14) + ctr)*8);
        const float4* pn = (const float4*)(xf + ((size_t)(b<<14) + nbr)*8);
        float4 c0 = pc[0], c1 = pc[1], n0 = pn[0], n1 = pn[1];
        float d[8] = {n0.x-c0.x, n0.y-c0.y, n0.z-c0.z, n0.w-c0.w,
                      n1.x-c1.x, n1.y-c1.y, n1.z-c1.z, n1.w-c1.w};
#pragma unroll
        for (int c = 0; c < 32; ++c) {
            float z = 0.f;
#pragma unroll
            for (int k = 0; k < 8; ++k) z = fmaf(d[k], w[k*32+c], z);
            s[c] += z; q[c] = fmaf(z, z, q[c]);
        }
    }
#pragma unroll
    for (int off = 32; off >= 1; off >>= 1) {
#pragma unroll
        for (int c = 0; c < 32; ++c) {
            s[c] += __shfl_xor(s[c], off, 64);
            q[c] += __shfl_xor(q[c], off, 64);
        }
    }
    if ((tid & 63) == 0) {
#pragma unroll
        for (int c = 0; c < 32; ++c) { atomicAdd(&red[c], s[c]); atomicAdd(&red[32+c], q[c]); }
    }
    __syncthreads();
    if (tid < 64) atomicAdd(&S[tid], red[tid]);
}

// ---------------- layer 0 edge MLP: apply + segment-max + add ----------------
__global__ __launch_bounds__(256) void k_edge_apply(const float* __restrict__ xf,
                                                    const int* __restrict__ ei,
                                                    const float* __restrict__ W,
                                                    const float* __restrict__ SS,
                                                    float* __restrict__ x0) {
    __shared__ float w[256];
    __shared__ float scs[32], shs[32];
    int tid = threadIdx.x;
    w[tid] = W[tid];
    if (tid < 32) { scs[tid] = SS[tid]; shs[tid] = SS[32+tid]; }
    __syncthreads();
    int r = blockIdx.x*256 + tid;
    int b = r >> 14, n = r & (NN-1);
    const int* nb = ei + (size_t)b*2*EE + EE + n*KK;
    const float4* pc = (const float4*)(xf + (size_t)r*8);
    float4 c0 = pc[0], c1 = pc[1];
    float mx[32];
#pragma unroll
    for (int c = 0; c < 32; ++c) mx[c] = -3.0e38f;
    for (int k = 0; k < KK; ++k) {
        int j = nb[k];
        const float4* pn = (const float4*)(xf + ((size_t)(b<<14) + j)*8);
        float4 n0 = pn[0], n1 = pn[1];
        float d[8] = {n0.x-c0.x, n0.y-c0.y, n0.z-c0.z, n0.w-c0.w,
                      n1.x-c1.x, n1.y-c1.y, n1.z-c1.z, n1.w-c1.w};
#pragma unroll
        for (int c = 0; c < 32; ++c) {
            float z = 0.f;
#pragma unroll
            for (int k2 = 0; k2 < 8; ++k2) z = fmaf(d[k2], w[k2*32+c], z);
            float y = lrelu(fmaf(z, scs[c], shs[c]));
            mx[c] = fmaxf(mx[c], y);
        }
    }
    float4* xp = (float4*)(x0 + (size_t)r*32);
#pragma unroll
    for (int i = 0; i < 8; ++i) {
        float4 v = xp[i];
        v.x += mx[i*4+0]; v.y += mx[i*4+1]; v.z += mx[i*4+2]; v.w += mx[i*4+3];
        xp[i] = v;
    }
}

// ---------------- generic GEMM: Z[R,CO] = X[R,CI] @ W[CI,CO] ----------------
template<int CI, int CO>
__global__ __launch_bounds__(256) void k_gemm(const float* __restrict__ X,
                                              const float* __restrict__ W,
                                              float* __restrict__ Z) {
    constexpr int CPG = CO/8;       // colgroups (thread owns 4 cols in each CO/2 half)
    constexpr int RG  = 256/CPG;    // rowgroups
    constexpr int TM  = 8;
    constexpr int BM  = RG*TM;      // rows per block
    constexpr int BK  = 32;
    constexpr int XP  = BK + 4;     // padded X row (float4-alignable)
    __shared__ float Xs[BM*XP];
    __shared__ float Ws[BK*CO];
    int tid = threadIdx.x;
    int g = tid % CPG, rg = tid / CPG;
    int cA = g*4, cB = CO/2 + g*4;
    size_t rowbase = (size_t)blockIdx.x*BM;
    float4 accA[TM], accB[TM];
#pragma unroll
    for (int m = 0; m < TM; ++m) {
        accA[m] = make_float4(0.f,0.f,0.f,0.f);
        accB[m] = make_float4(0.f,0.f,0.f,0.f);
    }
    for (int kk = 0; kk < CI; kk += BK) {
        for (int u = tid; u < BM*8; u += 256) {
            int i = u >> 3, j4 = (u & 7) << 2;
            *(float4*)&Xs[i*XP + j4] = *(const float4*)&X[(rowbase + i)*CI + kk + j4];
        }
        for (int u = tid; u < BK*CO/4; u += 256) {
            *(float4*)&Ws[u*4] = *(const float4*)&W[(size_t)kk*CO + u*4];
        }
        __syncthreads();
#pragma unroll 4
        for (int k = 0; k < BK; ++k) {
            float4 wA = *(const float4*)&Ws[k*CO + cA];
            float4 wB = *(const float4*)&Ws[k*CO + cB];
#pragma unroll
            for (int m = 0; m < TM; ++m) {
                float xv = Xs[(rg + RG*m)*XP + k];  // row-interleave: <=2-way bank alias
                accA[m].x = fmaf(xv, wA.x, accA[m].x);
                accA[m].y = fmaf(xv, wA.y, accA[m].y);
                accA[m].z = fmaf(xv, wA.z, accA[m].z);
                accA[m].w = fmaf(xv, wA.w, accA[m].w);
                accB[m].x = fmaf(xv, wB.x, accB[m].x);
                accB[m].y = fmaf(xv, wB.y, accB[m].y);
                accB[m].z = fmaf(xv, wB.z, accB[m].z);
                accB[m].w = fmaf(xv, wB.w, accB[m].w);
            }
        }
        __syncthreads();
    }
#pragma unroll
    for (int m = 0; m < TM; ++m) {
        size_t row = rowbase + rg + RG*m;
        *(float4*)&Z[row*CO + cA] = accA[m];
        *(float4*)&Z[row*CO + cB] = accB[m];
    }
}

// ---------------- gather 8 neighbors, max, add into a-branch ----------------
template<int CO>
__global__ __launch_bounds__(256) void k_gathermax(float* __restrict__ xi,
                                                   const float* __restrict__ xb,
                                                   const int* __restrict__ ei) {
    constexpr int CQ = CO/4;
    int t = blockIdx.x*256 + threadIdx.x;   // over RR*CQ
    int r = t / CQ;
    int c4 = (t % CQ)*4;
    int b = r >> 14, n = r & (NN-1);
    const int* nb = ei + (size_t)b*2*EE + EE + n*KK;
    float4 mx = make_float4(-3e38f,-3e38f,-3e38f,-3e38f);
#pragma unroll
    for (int k = 0; k < KK; ++k) {
        int j = nb[k];
        float4 v = *(const float4*)&xb[((size_t)(b<<14) + j)*CO + c4];
        mx.x = fmaxf(mx.x, v.x); mx.y = fmaxf(mx.y, v.y);
        mx.z = fmaxf(mx.z, v.z); mx.w = fmaxf(mx.w, v.w);
    }
    float4* op = (float4*)&xi[(size_t)r*CO + c4];
    float4 o = *op;
    o.x += mx.x; o.y += mx.y; o.z += mx.z; o.w += mx.w;
    *op = o;
}

// ---------------- concat @ Wcat dot (one wave per row) ----------------
__global__ __launch_bounds__(256) void k_catdot(const float* __restrict__ x0,
                                                const float* __restrict__ x1,
                                                const float* __restrict__ x2,
                                                const float* __restrict__ x3,
                                                const float* __restrict__ Wc,
                                                float* __restrict__ zc) {
    int r = blockIdx.x*4 + (threadIdx.x >> 6);
    int l = threadIdx.x & 63;
    float s = 0.f;
    if (l < 32) s = x0[(size_t)r*32 + l]*Wc[l];
    s = fmaf(x1[(size_t)r*64 + l], Wc[32+l], s);
    s = fmaf(x2[(size_t)r*128 + l],      Wc[96+l],  s);
    s = fmaf(x2[(size_t)r*128 + 64 + l], Wc[160+l], s);
#pragma unroll
    for (int qd = 0; qd < 4; ++qd)
        s = fmaf(x3[(size_t)r*256 + qd*64 + l], Wc[224 + qd*64 + l], s);
#pragma unroll
    for (int off = 32; off >= 1; off >>= 1) s += __shfl_xor(s, off, 64);
    if (l == 0) zc[r] = s;
}

// ---------------- final: BN(1 col) + leaky + bias ----------------
__global__ __launch_bounds__(256) void k_catfinal(const float* __restrict__ zc,
                                                  const float* __restrict__ S,
                                                  const float* __restrict__ g,
                                                  const float* __restrict__ bb,
                                                  const float* __restrict__ bias,
                                                  float* __restrict__ out) {
    int r = blockIdx.x*256 + threadIdx.x;
    const float invR = 1.f/65536.f;
    float m = S[0]*invR;
    float v = fmaxf(S[1]*invR - m*m, 0.f);
    float sc = g[0]*rsqrtf(v + 1e-5f);
    float sh = fmaf(-m, sc, bb[0]);
    float y = lrelu(fmaf(zc[r], sc, sh));
    out[r] = y + bias[0];
}

extern "C" void kernel_launch(void* const* d_in, const int* in_sizes, int n_in,
                              void* d_out, int out_size, void* d_ws, size_t ws_size,
                              hipStream_t stream) {
    const float* x    = (const float*)d_in[0];
    const int*   ei   = (const int*)d_in[1];
    const float* W0a  = (const float*)d_in[2];
    const float* g0a  = (const float*)d_in[3];
    const float* b0a  = (const float*)d_in[4];
    const float* W0b  = (const float*)d_in[5];
    const float* g0b  = (const float*)d_in[6];
    const float* b0b  = (const float*)d_in[7];
    const float* W1a  = (const float*)d_in[8];
    const float* g1a  = (const float*)d_in[9];
    const float* b1a  = (const float*)d_in[10];
    const float* W1b  = (const float*)d_in[11];
    const float* g1b  = (const float*)d_in[12];
    const float* b1b  = (const float*)d_in[13];
    const float* W2a  = (const float*)d_in[14];
    const float* g2a  = (const float*)d_in[15];
    const float* b2a  = (const float*)d_in[16];
    const float* W2b  = (const float*)d_in[17];
    const float* g2b  = (const float*)d_in[18];
    const float* b2b  = (const float*)d_in[19];
    const float* W3a  = (const float*)d_in[20];
    const float* g3a  = (const float*)d_in[21];
    const float* b3a  = (const float*)d_in[22];
    const float* W3b  = (const float*)d_in[23];
    const float* g3b  = (const float*)d_in[24];
    const float* b3b  = (const float*)d_in[25];
    const float* Wcat = (const float*)d_in[26];
    const float* gcat = (const float*)d_in[27];
    const float* bcat = (const float*)d_in[28];
    const float* bias = (const float*)d_in[29];
    float* out = (float*)d_out;

    float* ws = (float*)d_ws;
    float* x0 = ws + OFF_X0;
    float* x1 = ws + OFF_X1;
    float* x2 = ws + OFF_X2;
    float* x3 = ws + OFF_X3;
    float* zb = ws + OFF_ZB;
    float* zc = ws + OFF_ZC;
    float* S  = ws + OFF_S;
    float* SS = ws + OFF_SS;
    auto Sl  = [&](int i) { return S  + i*512; };
    auto SSl = [&](int i) { return SS + i*512; };

    const float invR = 1.f/(float)RR;
    const float invE = 1.f/(float)EG;

    hipMemsetAsync(S, 0, 9*512*sizeof(float), stream);

    // ---- layer 0 ----
    k_l0_node<<<RR/256, 256, 0, stream>>>(x, W0a, x0);
    k_colstats<32><<<512, 256, 0, stream>>>(x0, RR, Sl(0));
    k_finalize<<<1, 256, 0, stream>>>(Sl(0), g0a, b0a, invR, SSl(0), 32);
    k_bn_act<32><<<RR*32/4/256, 256, 0, stream>>>(x0, SSl(0), RR*32/4);
    k_edge_stats<<<256, 256, 0, stream>>>(x, ei, W0b, Sl(1));
    k_finalize<<<1, 256, 0, stream>>>(Sl(1), g0b, b0b, invE, SSl(1), 32);
    k_edge_apply<<<RR/256, 256, 0, stream>>>(x, ei, W0b, SSl(1), x0);

    // ---- layer 1: 32 -> 64 ----
    k_gemm<32,64><<<RR/256, 256, 0, stream>>>(x0, W1a, x1);
    k_gemm<32,64><<<RR/256, 256, 0, stream>>>(x0, W1b, zb);
    k_colstats<64><<<512, 256, 0, stream>>>(x1, RR, Sl(2));
    k_colstats<64><<<512, 256, 0, stream>>>(zb, RR, Sl(3));
    k_finalize<<<1, 256, 0, stream>>>(Sl(2), g1a, b1a, invR, SSl(2), 64);
    k_finalize<<<1, 256, 0, stream>>>(Sl(3), g1b, b1b, invR, SSl(3), 64);
    k_bn_act<64><<<RR*64/4/256, 256, 0, stream>>>(x1, SSl(2), RR*64/4);
    k_bn_act<64><<<RR*64/4/256, 256, 0, stream>>>(zb, SSl(3), RR*64/4);
    k_gathermax<64><<<RR*16/256, 256, 0, stream>>>(x1, zb, ei);

    // ---- layer 2: 64 -> 128 ----
    k_gemm<64,128><<<RR/128, 256, 0, stream>>>(x1, W2a, x2);
    k_gemm<64,128><<<RR/128, 256, 0, stream>>>(x1, W2b, zb);
    k_colstats<128><<<512, 256, 0, stream>>>(x2, RR, Sl(4));
    k_colstats<128><<<512, 256, 0, stream>>>(zb, RR, Sl(5));
    k_finalize<<<1, 256, 0, stream>>>(Sl(4), g2a, b2a, invR, SSl(4), 128);
    k_finalize<<<1, 256, 0, stream>>>(Sl(5), g2b, b2b, invR, SSl(5), 128);
    k_bn_act<128><<<RR*128/4/256, 256, 0, stream>>>(x2, SSl(4), RR*128/4);
    k_bn_act<128><<<RR*128/4/256, 256, 0, stream>>>(zb, SSl(5), RR*128/4);
    k_gathermax<128><<<RR*32/256, 256, 0, stream>>>(x2, zb, ei);

    // ---- layer 3: 128 -> 256 ----
    k_gemm<128,256><<<RR/64, 256, 0, stream>>>(x2, W3a, x3);
    k_gemm<128,256><<<RR/64, 256, 0, stream>>>(x2, W3b, zb);
    k_colstats<256><<<512, 256, 0, stream>>>(x3, RR, Sl(6));
    k_colstats<256><<<512, 256, 0, stream>>>(zb, RR, Sl(7));
    k_finalize<<<1, 256, 0, stream>>>(Sl(6), g3a, b3a, invR, SSl(6), 256);
    k_finalize<<<1, 256, 0, stream>>>(Sl(7), g3b, b3b, invR, SSl(7), 256);
    k_bn_act<256><<<RR*256/4/256, 256, 0, stream>>>(x3, SSl(6), RR*256/4);
    k_bn_act<256><<<RR*256/4/256, 256, 0, stream>>>(zb, SSl(7), RR*256/4);
    k_gathermax<256><<<RR*64/256, 256, 0, stream>>>(x3, zb, ei);

    // ---- cat head ----
    k_catdot<<<RR/4, 256, 0, stream>>>(x0, x1, x2, x3, Wcat, zc);
    k_colstats<1><<<512, 256, 0, stream>>>(zc, RR, Sl(8));
    k_catfinal<<<RR/256, 256, 0, stream>>>(zc, Sl(8), gcat, bcat, bias, out);
}

// Round 2
// 561.872 us; speedup vs baseline: 1.4201x; 1.4201x over previous
//
#include <hip/hip_runtime.h>
#include <math.h>

// Problem constants
static constexpr int BB = 4;        // batch
static constexpr int NN = 16384;    // nodes per batch
static constexpr int KK = 8;        // neighbors per node
static constexpr int EE = 131072;   // edges per batch = NN*KK
static constexpr int RR = 65536;    // BB*NN rows
static constexpr int EG = 524288;   // BB*EE edges total

// Workspace layout (float offsets)
static constexpr size_t OFF_X0 = 0;                      // 65536*32 fp32
static constexpr size_t OFF_X1 = OFF_X0 + (size_t)RR*32; // 65536*64 fp32
static constexpr size_t OFF_X2 = OFF_X1 + (size_t)RR*64; // 65536*128 fp32
static constexpr size_t OFF_X3 = OFF_X2 + (size_t)RR*128;// 65536*256 fp32
static constexpr size_t OFF_ZB = OFF_X3 + (size_t)RR*256;// 65536*256 *bf16* (b-branch)
static constexpr size_t OFF_ZC = OFF_ZB + (size_t)RR*128;// 65536 fp32 (ZB uses half: bf16)
static constexpr size_t OFF_S  = OFF_ZC + (size_t)RR;    // 9 slots * 512
static constexpr size_t OFF_SS = OFF_S + 9*512;          // 9 slots * 512

__device__ __forceinline__ float lrelu(float x) { return fmaxf(x, 0.2f*x); }

__device__ __forceinline__ unsigned short f2bf(float f) {
    unsigned u = __float_as_uint(f);
    unsigned r = (u + 0x7FFFu + ((u >> 16) & 1u)) >> 16;
    return (unsigned short)r;
}
__device__ __forceinline__ float bf2f(unsigned short h) {
    return __uint_as_float(((unsigned)h) << 16);
}

// ---------------- layer 0: node GEMM 8->32 (pre-BN) + fused col stats ----------------
__global__ __launch_bounds__(256) void k_l0_node(const float* __restrict__ xf,
                                                 const float* __restrict__ W,
                                                 float* __restrict__ z,
                                                 float* __restrict__ S) {
    __shared__ float w[256];
    __shared__ float red[64];
    int tid = threadIdx.x;
    w[tid] = W[tid];
    if (tid < 64) red[tid] = 0.f;
    __syncthreads();
    int r = blockIdx.x*256 + tid;
    const float4* xr = (const float4*)(xf + (size_t)r*8);
    float4 a = xr[0], b = xr[1];
    float xv[8] = {a.x,a.y,a.z,a.w,b.x,b.y,b.z,b.w};
    float op[32];
#pragma unroll
    for (int c = 0; c < 32; ++c) {
        float s = 0.f;
#pragma unroll
        for (int k = 0; k < 8; ++k) s = fmaf(xv[k], w[k*32+c], s);
        op[c] = s;
    }
    float4* zp = (float4*)(z + (size_t)r*32);
#pragma unroll
    for (int i = 0; i < 8; ++i)
        zp[i] = make_float4(op[i*4], op[i*4+1], op[i*4+2], op[i*4+3]);
    // stats: shuffle-reduce each column over the wave, LDS-atomic across waves
#pragma unroll
    for (int c = 0; c < 32; ++c) {
        float s = op[c], q = op[c]*op[c];
#pragma unroll
        for (int off = 32; off >= 1; off >>= 1) {
            s += __shfl_xor(s, off, 64);
            q += __shfl_xor(q, off, 64);
        }
        if ((tid & 63) == 0) { atomicAdd(&red[c], s); atomicAdd(&red[32+c], q); }
    }
    __syncthreads();
    if (tid < 64) atomicAdd(&S[tid], red[tid]);
}

// ---------------- column stats (only for the 1-col cat head) ----------------
template<int C>
__global__ __launch_bounds__(256) void k_colstats(const float* __restrict__ Z, int R,
                                                  float* __restrict__ S) {
    constexpr int TPC = 256 / C;
    __shared__ float ls[256];
    __shared__ float lq[256];
    int tid = threadIdx.x;
    int c = tid % C, rr = tid / C;
    float s = 0.f, q = 0.f;
    for (int r = blockIdx.x*TPC + rr; r < R; r += gridDim.x*TPC) {
        float v = Z[(size_t)r*C + c];
        s += v; q = fmaf(v, v, q);
    }
    ls[tid] = s; lq[tid] = q;
    __syncthreads();
#pragma unroll
    for (int half = TPC/2; half >= 1; half >>= 1) {
        if (rr < half) { ls[tid] += ls[tid + half*C]; lq[tid] += lq[tid + half*C]; }
        __syncthreads();
    }
    if (rr == 0) { atomicAdd(&S[c], ls[tid]); atomicAdd(&S[C+c], lq[tid]); }
}

// ---------------- finalize (two BN slots in one launch) ----------------
__global__ void k_finalize2(const float* __restrict__ Sa, const float* __restrict__ ga,
                            const float* __restrict__ ba, float invA,
                            float* __restrict__ SSa, int Ca,
                            const float* __restrict__ Sb, const float* __restrict__ gb,
                            const float* __restrict__ bb, float invB,
                            float* __restrict__ SSb, int Cb) {
    int t = threadIdx.x;
    if (t < Ca) {
        float m = Sa[t]*invA;
        float v = fmaxf(Sa[Ca+t]*invA - m*m, 0.f);
        float sc = ga[t]*rsqrtf(v + 1e-5f);
        SSa[t] = sc;
        SSa[Ca+t] = fmaf(-m, sc, ba[t]);
    }
    int u = t - 256;
    if (u >= 0 && u < Cb) {
        float m = Sb[u]*invB;
        float v = fmaxf(Sb[Cb+u]*invB - m*m, 0.f);
        float sc = gb[u]*rsqrtf(v + 1e-5f);
        SSb[u] = sc;
        SSb[Cb+u] = fmaf(-m, sc, bb[u]);
    }
}

// ---------------- layer 0 edge MLP: stats pass ----------------
__global__ __launch_bounds__(256) void k_edge_stats(const float* __restrict__ xf,
                                                    const int* __restrict__ ei,
                                                    const float* __restrict__ W,
                                                    float* __restrict__ S) {
    __shared__ float w[256];
    __shared__ float red[64];
    int tid = threadIdx.x;
    w[tid] = W[tid];
    if (tid < 64) red[tid] = 0.f;
    __syncthreads();
    float s[32], q[32];
#pragma unroll
    for (int c = 0; c < 32; ++c) { s[c] = 0.f; q[c] = 0.f; }
    for (int e = blockIdx.x*256 + tid; e < EG; e += gridDim.x*256) {
        int b = e >> 17, j = e & (EE-1);
        const int* base = ei + (size_t)b*2*EE;
        int ctr = base[j], nbr = base[EE + j];
        const float4* pc = (const float4*)(xf + ((size_t)(b<<14) + ctr)*8);
        const float4* pn = (const float4*)(xf + ((size_t)(b<<14) + nbr)*8);
        float4 c0 = pc[0], c1 = pc[1], n0 = pn[0], n1 = pn[1];
        float d[8] = {n0.x-c0.x, n0.y-c0.y, n0.z-c0.z, n0.w-c0.w,
                      n1.x-c1.x, n1.y-c1.y, n1.z-c1.z, n1.w-c1.w};
#pragma unroll
        for (int c = 0; c < 32; ++c) {
            float z = 0.f;
#pragma unroll
            for (int k = 0; k < 8; ++k) z = fmaf(d[k], w[k*32+c], z);
            s[c] += z; q[c] = fmaf(z, z, q[c]);
        }
    }
#pragma unroll
    for (int off = 32; off >= 1; off >>= 1) {
#pragma unroll
        for (int c = 0; c < 32; ++c) {
            s[c] += __shfl_xor(s[c], off, 64);
            q[c] += __shfl_xor(q[c], off, 64);
        }
    }
    if ((tid & 63) == 0) {
#pragma unroll
        for (int c = 0; c < 32; ++c) { atomicAdd(&red[c], s[c]); atomicAdd(&red[32+c], q[c]); }
    }
    __syncthreads();
    if (tid < 64) atomicAdd(&S[tid], red[tid]);
}

// ---- layer 0 edge apply: BNa(x0raw)+lrelu + edge MLP max, write x0 final ----
__global__ __launch_bounds__(256) void k_edge_apply(const float* __restrict__ xf,
                                                    const int* __restrict__ ei,
                                                    const float* __restrict__ W,
                                                    const float* __restrict__ SSa,
                                                    const float* __restrict__ SSb,
                                                    float* __restrict__ x0) {
    __shared__ float w[256];
    __shared__ float scb[32], shb[32], sca[32], sha[32];
    int tid = threadIdx.x;
    w[tid] = W[tid];
    if (tid < 32) {
        scb[tid] = SSb[tid]; shb[tid] = SSb[32+tid];
        sca[tid] = SSa[tid]; sha[tid] = SSa[32+tid];
    }
    __syncthreads();
    int r = blockIdx.x*256 + tid;
    int b = r >> 14, n = r & (NN-1);
    const int* nb = ei + (size_t)b*2*EE + EE + n*KK;
    const float4* pc = (const float4*)(xf + (size_t)r*8);
    float4 c0 = pc[0], c1 = pc[1];
    float mx[32];
#pragma unroll
    for (int c = 0; c < 32; ++c) mx[c] = -3.0e38f;
    for (int k = 0; k < KK; ++k) {
        int j = nb[k];
        const float4* pn = (const float4*)(xf + ((size_t)(b<<14) + j)*8);
        float4 n0 = pn[0], n1 = pn[1];
        float d[8] = {n0.x-c0.x, n0.y-c0.y, n0.z-c0.z, n0.w-c0.w,
                      n1.x-c1.x, n1.y-c1.y, n1.z-c1.z, n1.w-c1.w};
#pragma unroll
        for (int c = 0; c < 32; ++c) {
            float z = 0.f;
#pragma unroll
            for (int k2 = 0; k2 < 8; ++k2) z = fmaf(d[k2], w[k2*32+c], z);
            float y = lrelu(fmaf(z, scb[c], shb[c]));
            mx[c] = fmaxf(mx[c], y);
        }
    }
    float4* xp = (float4*)(x0 + (size_t)r*32);
#pragma unroll
    for (int i = 0; i < 8; ++i) {
        float4 v = xp[i];
        v.x = lrelu(fmaf(v.x, sca[i*4+0], sha[i*4+0])) + mx[i*4+0];
        v.y = lrelu(fmaf(v.y, sca[i*4+1], sha[i*4+1])) + mx[i*4+1];
        v.z = lrelu(fmaf(v.z, sca[i*4+2], sha[i*4+2])) + mx[i*4+2];
        v.w = lrelu(fmaf(v.w, sca[i*4+3], sha[i*4+3])) + mx[i*4+3];
        xp[i] = v;
    }
}

// ---- generic GEMM: Z[R,CO] = X[R,CI] @ W[CI,CO], fused col stats, opt bf16 out ----
template<int CI, int CO, bool BF16OUT>
__global__ __launch_bounds__(256) void k_gemm(const float* __restrict__ X,
                                              const float* __restrict__ W,
                                              void* __restrict__ Zv,
                                              float* __restrict__ Sg) {
    constexpr int CPG = CO/8;
    constexpr int RG  = 256/CPG;
    constexpr int TM  = 8;
    constexpr int BM  = RG*TM;
    constexpr int BK  = 32;
    constexpr int XP  = BK + 4;
    __shared__ float Xs[BM*XP];
    __shared__ float Ws[BK*CO];
    __shared__ float sred[2*CO];
    int tid = threadIdx.x;
    for (int u = tid; u < 2*CO; u += 256) sred[u] = 0.f;
    int g = tid % CPG, rg = tid / CPG;
    int cA = g*4, cB = CO/2 + g*4;
    size_t rowbase = (size_t)blockIdx.x*BM;
    float4 accA[TM], accB[TM];
#pragma unroll
    for (int m = 0; m < TM; ++m) {
        accA[m] = make_float4(0.f,0.f,0.f,0.f);
        accB[m] = make_float4(0.f,0.f,0.f,0.f);
    }
    for (int kk = 0; kk < CI; kk += BK) {
        for (int u = tid; u < BM*8; u += 256) {
            int i = u >> 3, j4 = (u & 7) << 2;
            *(float4*)&Xs[i*XP + j4] = *(const float4*)&X[(rowbase + i)*CI + kk + j4];
        }
        for (int u = tid; u < BK*CO/4; u += 256) {
            *(float4*)&Ws[u*4] = *(const float4*)&W[(size_t)kk*CO + u*4];
        }
        __syncthreads();
#pragma unroll 4
        for (int k = 0; k < BK; ++k) {
            float4 wA = *(const float4*)&Ws[k*CO + cA];
            float4 wB = *(const float4*)&Ws[k*CO + cB];
#pragma unroll
            for (int m = 0; m < TM; ++m) {
                float xv = Xs[(rg + RG*m)*XP + k];
                accA[m].x = fmaf(xv, wA.x, accA[m].x);
                accA[m].y = fmaf(xv, wA.y, accA[m].y);
                accA[m].z = fmaf(xv, wA.z, accA[m].z);
                accA[m].w = fmaf(xv, wA.w, accA[m].w);
                accB[m].x = fmaf(xv, wB.x, accB[m].x);
                accB[m].y = fmaf(xv, wB.y, accB[m].y);
                accB[m].z = fmaf(xv, wB.z, accB[m].z);
                accB[m].w = fmaf(xv, wB.w, accB[m].w);
            }
        }
        __syncthreads();
    }
    // store
#pragma unroll
    for (int m = 0; m < TM; ++m) {
        size_t row = rowbase + rg + RG*m;
        if (BF16OUT) {
            unsigned short* Z = (unsigned short*)Zv;
            ushort4 hA = { f2bf(accA[m].x), f2bf(accA[m].y), f2bf(accA[m].z), f2bf(accA[m].w) };
            ushort4 hB = { f2bf(accB[m].x), f2bf(accB[m].y), f2bf(accB[m].z), f2bf(accB[m].w) };
            *(ushort4*)&Z[row*CO + cA] = hA;
            *(ushort4*)&Z[row*CO + cB] = hB;
        } else {
            float* Z = (float*)Zv;
            *(float4*)&Z[row*CO + cA] = accA[m];
            *(float4*)&Z[row*CO + cB] = accB[m];
        }
    }
    // fused column stats: per-thread partials -> LDS atomics -> global atomics
    float4 sA = make_float4(0,0,0,0), qA = sA, sB = sA, qB = sA;
#pragma unroll
    for (int m = 0; m < TM; ++m) {
        sA.x += accA[m].x; qA.x = fmaf(accA[m].x, accA[m].x, qA.x);
        sA.y += accA[m].y; qA.y = fmaf(accA[m].y, accA[m].y, qA.y);
        sA.z += accA[m].z; qA.z = fmaf(accA[m].z, accA[m].z, qA.z);
        sA.w += accA[m].w; qA.w = fmaf(accA[m].w, accA[m].w, qA.w);
        sB.x += accB[m].x; qB.x = fmaf(accB[m].x, accB[m].x, qB.x);
        sB.y += accB[m].y; qB.y = fmaf(accB[m].y, accB[m].y, qB.y);
        sB.z += accB[m].z; qB.z = fmaf(accB[m].z, accB[m].z, qB.z);
        sB.w += accB[m].w; qB.w = fmaf(accB[m].w, accB[m].w, qB.w);
    }
    atomicAdd(&sred[cA+0], sA.x); atomicAdd(&sred[CO+cA+0], qA.x);
    atomicAdd(&sred[cA+1], sA.y); atomicAdd(&sred[CO+cA+1], qA.y);
    atomicAdd(&sred[cA+2], sA.z); atomicAdd(&sred[CO+cA+2], qA.z);
    atomicAdd(&sred[cA+3], sA.w); atomicAdd(&sred[CO+cA+3], qA.w);
    atomicAdd(&sred[cB+0], sB.x); atomicAdd(&sred[CO+cB+0], qB.x);
    atomicAdd(&sred[cB+1], sB.y); atomicAdd(&sred[CO+cB+1], qB.y);
    atomicAdd(&sred[cB+2], sB.z); atomicAdd(&sred[CO+cB+2], qB.z);
    atomicAdd(&sred[cB+3], sB.w); atomicAdd(&sred[CO+cB+3], qB.w);
    __syncthreads();
    for (int u = tid; u < CO; u += 256) {
        atomicAdd(&Sg[u], sred[u]);
        atomicAdd(&Sg[CO+u], sred[CO+u]);
    }
}

// ---- fused: BNa+lrelu on center row, gather 8 nbrs from bf16 zb w/ BNb+lrelu, max, add ----
template<int CO>
__global__ __launch_bounds__(256) void k_gathermax(float* __restrict__ xi,
                                                   const unsigned short* __restrict__ zbh,
                                                   const int* __restrict__ ei,
                                                   const float* __restrict__ SSa,
                                                   const float* __restrict__ SSb) {
    constexpr int CQ = CO/8;
    int t = blockIdx.x*256 + threadIdx.x;
    int r = t / CQ;
    int c8 = (t % CQ)*8;
    int b = r >> 14, n = r & (NN-1);
    const int* nb = ei + (size_t)b*2*EE + EE + n*KK;
    float4 sb0 = *(const float4*)&SSb[c8],    sb1 = *(const float4*)&SSb[c8+4];
    float4 hb0 = *(const float4*)&SSb[CO+c8], hb1 = *(const float4*)&SSb[CO+c8+4];
    int nbr[KK];
#pragma unroll
    for (int k = 0; k < KK; ++k) nbr[k] = nb[k];
    size_t bbase = ((size_t)(b<<14))*CO + c8;
    float4 mx0 = make_float4(-3e38f,-3e38f,-3e38f,-3e38f), mx1 = mx0;
#pragma unroll
    for (int k = 0; k < KK; ++k) {
        const unsigned short* p = zbh + bbase + (size_t)nbr[k]*CO;
        ushort4 u0 = *(const ushort4*)p;
        ushort4 u1 = *(const ushort4*)(p+4);
        mx0.x = fmaxf(mx0.x, lrelu(fmaf(bf2f(u0.x), sb0.x, hb0.x)));
        mx0.y = fmaxf(mx0.y, lrelu(fmaf(bf2f(u0.y), sb0.y, hb0.y)));
        mx0.z = fmaxf(mx0.z, lrelu(fmaf(bf2f(u0.z), sb0.z, hb0.z)));
        mx0.w = fmaxf(mx0.w, lrelu(fmaf(bf2f(u0.w), sb0.w, hb0.w)));
        mx1.x = fmaxf(mx1.x, lrelu(fmaf(bf2f(u1.x), sb1.x, hb1.x)));
        mx1.y = fmaxf(mx1.y, lrelu(fmaf(bf2f(u1.y), sb1.y, hb1.y)));
        mx1.z = fmaxf(mx1.z, lrelu(fmaf(bf2f(u1.z), sb1.z, hb1.z)));
        mx1.w = fmaxf(mx1.w, lrelu(fmaf(bf2f(u1.w), sb1.w, hb1.w)));
    }
    float4 sa0 = *(const float4*)&SSa[c8],    sa1 = *(const float4*)&SSa[c8+4];
    float4 ha0 = *(const float4*)&SSa[CO+c8], ha1 = *(const float4*)&SSa[CO+c8+4];
    float4* xp0 = (float4*)&xi[(size_t)r*CO + c8];
    float4* xp1 = xp0 + 1;
    float4 a0 = *xp0, a1 = *xp1;
    a0.x = lrelu(fmaf(a0.x, sa0.x, ha0.x)) + mx0.x;
    a0.y = lrelu(fmaf(a0.y, sa0.y, ha0.y)) + mx0.y;
    a0.z = lrelu(fmaf(a0.z, sa0.z, ha0.z)) + mx0.z;
    a0.w = lrelu(fmaf(a0.w, sa0.w, ha0.w)) + mx0.w;
    a1.x = lrelu(fmaf(a1.x, sa1.x, ha1.x)) + mx1.x;
    a1.y = lrelu(fmaf(a1.y, sa1.y, ha1.y)) + mx1.y;
    a1.z = lrelu(fmaf(a1.z, sa1.z, ha1.z)) + mx1.z;
    a1.w = lrelu(fmaf(a1.w, sa1.w, ha1.w)) + mx1.w;
    *xp0 = a0;
    *xp1 = a1;
}

// ---------------- concat @ Wcat dot (one wave per row) ----------------
__global__ __launch_bounds__(256) void k_catdot(const float* __restrict__ x0,
                                                const float* __restrict__ x1,
                                                const float* __restrict__ x2,
                                                const float* __restrict__ x3,
                                                const float* __restrict__ Wc,
                                                float* __restrict__ zc) {
    int r = blockIdx.x*4 + (threadIdx.x >> 6);
    int l = threadIdx.x & 63;
    float s = 0.f;
    if (l < 32) s = x0[(size_t)r*32 + l]*Wc[l];
    s = fmaf(x1[(size_t)r*64 + l], Wc[32+l], s);
    s = fmaf(x2[(size_t)r*128 + l],      Wc[96+l],  s);
    s = fmaf(x2[(size_t)r*128 + 64 + l], Wc[160+l], s);
#pragma unroll
    for (int qd = 0; qd < 4; ++qd)
        s = fmaf(x3[(size_t)r*256 + qd*64 + l], Wc[224 + qd*64 + l], s);
#pragma unroll
    for (int off = 32; off >= 1; off >>= 1) s += __shfl_xor(s, off, 64);
    if (l == 0) zc[r] = s;
}

// ---------------- final: BN(1 col) + leaky + bias ----------------
__global__ __launch_bounds__(256) void k_catfinal(const float* __restrict__ zc,
                                                  const float* __restrict__ S,
                                                  const float* __restrict__ g,
                                                  const float* __restrict__ bb,
                                                  const float* __restrict__ bias,
                                                  float* __restrict__ out) {
    int r = blockIdx.x*256 + threadIdx.x;
    const float invR = 1.f/65536.f;
    float m = S[0]*invR;
    float v = fmaxf(S[1]*invR - m*m, 0.f);
    float sc = g[0]*rsqrtf(v + 1e-5f);
    float sh = fmaf(-m, sc, bb[0]);
    float y = lrelu(fmaf(zc[r], sc, sh));
    out[r] = y + bias[0];
}

extern "C" void kernel_launch(void* const* d_in, const int* in_sizes, int n_in,
                              void* d_out, int out_size, void* d_ws, size_t ws_size,
                              hipStream_t stream) {
    const float* x    = (const float*)d_in[0];
    const int*   ei   = (const int*)d_in[1];
    const float* W0a  = (const float*)d_in[2];
    const float* g0a  = (const float*)d_in[3];
    const float* b0a  = (const float*)d_in[4];
    const float* W0b  = (const float*)d_in[5];
    const float* g0b  = (const float*)d_in[6];
    const float* b0b  = (const float*)d_in[7];
    const float* W1a  = (const float*)d_in[8];
    const float* g1a  = (const float*)d_in[9];
    const float* b1a  = (const float*)d_in[10];
    const float* W1b  = (const float*)d_in[11];
    const float* g1b  = (const float*)d_in[12];
    const float* b1b  = (const float*)d_in[13];
    const float* W2a  = (const float*)d_in[14];
    const float* g2a  = (const float*)d_in[15];
    const float* b2a  = (const float*)d_in[16];
    const float* W2b  = (const float*)d_in[17];
    const float* g2b  = (const float*)d_in[18];
    const float* b2b  = (const float*)d_in[19];
    const float* W3a  = (const float*)d_in[20];
    const float* g3a  = (const float*)d_in[21];
    const float* b3a  = (const float*)d_in[22];
    const float* W3b  = (const float*)d_in[23];
    const float* g3b  = (const float*)d_in[24];
    const float* b3b  = (const float*)d_in[25];
    const float* Wcat = (const float*)d_in[26];
    const float* gcat = (const float*)d_in[27];
    const float* bcat = (const float*)d_in[28];
    const float* bias = (const float*)d_in[29];
    float* out = (float*)d_out;

    float* ws = (float*)d_ws;
    float* x0 = ws + OFF_X0;
    float* x1 = ws + OFF_X1;
    float* x2 = ws + OFF_X2;
    float* x3 = ws + OFF_X3;
    unsigned short* zbh = (unsigned short*)(ws + OFF_ZB);
    float* zc = ws + OFF_ZC;
    float* S  = ws + OFF_S;
    float* SS = ws + OFF_SS;
    auto Sl  = [&](int i) { return S  + i*512; };
    auto SSl = [&](int i) { return SS + i*512; };

    const float invR = 1.f/(float)RR;
    const float invE = 1.f/(float)EG;

    hipMemsetAsync(S, 0, 9*512*sizeof(float), stream);

    // ---- layer 0 ----
    k_l0_node<<<RR/256, 256, 0, stream>>>(x, W0a, x0, Sl(0));
    k_edge_stats<<<256, 256, 0, stream>>>(x, ei, W0b, Sl(1));
    k_finalize2<<<1, 512, 0, stream>>>(Sl(0), g0a, b0a, invR, SSl(0), 32,
                                       Sl(1), g0b, b0b, invE, SSl(1), 32);
    k_edge_apply<<<RR/256, 256, 0, stream>>>(x, ei, W0b, SSl(0), SSl(1), x0);

    // ---- layer 1: 32 -> 64 ----
    k_gemm<32,64,false><<<RR/256, 256, 0, stream>>>(x0, W1a, x1, Sl(2));
    k_gemm<32,64,true ><<<RR/256, 256, 0, stream>>>(x0, W1b, zbh, Sl(3));
    k_finalize2<<<1, 512, 0, stream>>>(Sl(2), g1a, b1a, invR, SSl(2), 64,
                                       Sl(3), g1b, b1b, invR, SSl(3), 64);
    k_gathermax<64><<<RR*8/256, 256, 0, stream>>>(x1, zbh, ei, SSl(2), SSl(3));

    // ---- layer 2: 64 -> 128 ----
    k_gemm<64,128,false><<<RR/128, 256, 0, stream>>>(x1, W2a, x2, Sl(4));
    k_gemm<64,128,true ><<<RR/128, 256, 0, stream>>>(x1, W2b, zbh, Sl(5));
    k_finalize2<<<1, 512, 0, stream>>>(Sl(4), g2a, b2a, invR, SSl(4), 128,
                                       Sl(5), g2b, b2b, invR, SSl(5), 128);
    k_gathermax<128><<<RR*16/256, 256, 0, stream>>>(x2, zbh, ei, SSl(4), SSl(5));

    // ---- layer 3: 128 -> 256 ----
    k_gemm<128,256,false><<<RR/64, 256, 0, stream>>>(x2, W3a, x3, Sl(6));
    k_gemm<128,256,true ><<<RR/64, 256, 0, stream>>>(x2, W3b, zbh, Sl(7));
    k_finalize2<<<1, 512, 0, stream>>>(Sl(6), g3a, b3a, invR, SSl(6), 256,
                                       Sl(7), g3b, b3b, invR, SSl(7), 256);
    k_gathermax<256><<<RR*32/256, 256, 0, stream>>>(x3, zbh, ei, SSl(6), SSl(7));

    // ---- cat head ----
    k_catdot<<<RR/4, 256, 0, stream>>>(x0, x1, x2, x3, Wcat, zc);
    k_colstats<1><<<512, 256, 0, stream>>>(zc, RR, Sl(8));
    k_catfinal<<<RR/256, 256, 0, stream>>>(zc, Sl(8), gcat, bcat, bias, out);
}

// Round 3
// 483.138 us; speedup vs baseline: 1.6515x; 1.1630x over previous
//
#include <hip/hip_runtime.h>
#include <math.h>

// Problem constants
static constexpr int BB = 4;        // batch
static constexpr int NN = 16384;    // nodes per batch
static constexpr int KK = 8;        // neighbors per node
static constexpr int EE = 131072;   // edges per batch = NN*KK
static constexpr int RR = 65536;    // BB*NN rows
static constexpr int EG = 524288;   // BB*EE edges total

// Workspace layout (float offsets)
static constexpr size_t OFF_X0 = 0;                      // 65536*32 fp32
static constexpr size_t OFF_X1 = OFF_X0 + (size_t)RR*32; // 65536*64 fp32
static constexpr size_t OFF_X2 = OFF_X1 + (size_t)RR*64; // 65536*128 fp32
static constexpr size_t OFF_X3 = OFF_X2 + (size_t)RR*128;// 65536*256 fp32
static constexpr size_t OFF_ZB = OFF_X3 + (size_t)RR*256;// 65536*256 *bf16* (b-branch)
static constexpr size_t OFF_ZC = OFF_ZB + (size_t)RR*128;// 65536 fp32
static constexpr size_t OFF_S  = OFF_ZC + (size_t)RR;    // 9 slots * 512
static constexpr size_t OFF_SS = OFF_S + 9*512;          // 9 slots * 512
static constexpr size_t OFF_WP = OFF_SS + 9*512;         // packed weights (ushort): see below
// packed weight offsets in ushorts relative to OFF_WP*2:
static constexpr size_t WP1_OFF = 0;              // 2*128*32  = 8192
static constexpr size_t WP2_OFF = 8192;           // 2*256*64  = 32768
static constexpr size_t WP3_OFF = 8192 + 32768;   // 2*512*128 = 131072

__device__ __forceinline__ float lrelu(float x) { return fmaxf(x, 0.2f*x); }

__device__ __forceinline__ unsigned short f2bf(float f) {
    unsigned u = __float_as_uint(f);
    unsigned r = (u + 0x7FFFu + ((u >> 16) & 1u)) >> 16;
    return (unsigned short)r;
}
__device__ __forceinline__ float bf2f(unsigned short h) {
    return __uint_as_float(((unsigned)h) << 16);
}

typedef __attribute__((ext_vector_type(8))) short short8v;
typedef __attribute__((ext_vector_type(4))) float float4v;

// ---------------- layer 0: node GEMM 8->32 (pre-BN) + fused col stats ----------------
__global__ __launch_bounds__(256) void k_l0_node(const float* __restrict__ xf,
                                                 const float* __restrict__ W,
                                                 float* __restrict__ z,
                                                 float* __restrict__ S) {
    __shared__ float w[256];
    __shared__ float red[64];
    int tid = threadIdx.x;
    w[tid] = W[tid];
    if (tid < 64) red[tid] = 0.f;
    __syncthreads();
    int r = blockIdx.x*256 + tid;
    const float4* xr = (const float4*)(xf + (size_t)r*8);
    float4 a = xr[0], b = xr[1];
    float xv[8] = {a.x,a.y,a.z,a.w,b.x,b.y,b.z,b.w};
    float op[32];
#pragma unroll
    for (int c = 0; c < 32; ++c) {
        float s = 0.f;
#pragma unroll
        for (int k = 0; k < 8; ++k) s = fmaf(xv[k], w[k*32+c], s);
        op[c] = s;
    }
    float4* zp = (float4*)(z + (size_t)r*32);
#pragma unroll
    for (int i = 0; i < 8; ++i)
        zp[i] = make_float4(op[i*4], op[i*4+1], op[i*4+2], op[i*4+3]);
#pragma unroll
    for (int c = 0; c < 32; ++c) {
        float s = op[c], q = op[c]*op[c];
#pragma unroll
        for (int off = 32; off >= 1; off >>= 1) {
            s += __shfl_xor(s, off, 64);
            q += __shfl_xor(q, off, 64);
        }
        if ((tid & 63) == 0) { atomicAdd(&red[c], s); atomicAdd(&red[32+c], q); }
    }
    __syncthreads();
    if (tid < 64) atomicAdd(&S[tid], red[tid]);
}

// ---------------- column stats (only for the 1-col cat head) ----------------
template<int C>
__global__ __launch_bounds__(256) void k_colstats(const float* __restrict__ Z, int R,
                                                  float* __restrict__ S) {
    constexpr int TPC = 256 / C;
    __shared__ float ls[256];
    __shared__ float lq[256];
    int tid = threadIdx.x;
    int c = tid % C, rr = tid / C;
    float s = 0.f, q = 0.f;
    for (int r = blockIdx.x*TPC + rr; r < R; r += gridDim.x*TPC) {
        float v = Z[(size_t)r*C + c];
        s += v; q = fmaf(v, v, q);
    }
    ls[tid] = s; lq[tid] = q;
    __syncthreads();
#pragma unroll
    for (int half = TPC/2; half >= 1; half >>= 1) {
        if (rr < half) { ls[tid] += ls[tid + half*C]; lq[tid] += lq[tid + half*C]; }
        __syncthreads();
    }
    if (rr == 0) { atomicAdd(&S[c], ls[tid]); atomicAdd(&S[C+c], lq[tid]); }
}

// ---------------- finalize (two BN slots in one launch) ----------------
__global__ void k_finalize2(const float* __restrict__ Sa, const float* __restrict__ ga,
                            const float* __restrict__ ba, float invA,
                            float* __restrict__ SSa, int Ca,
                            const float* __restrict__ Sb, const float* __restrict__ gb,
                            const float* __restrict__ bb, float invB,
                            float* __restrict__ SSb, int Cb) {
    int t = threadIdx.x;
    if (t < Ca) {
        float m = Sa[t]*invA;
        float v = fmaxf(Sa[Ca+t]*invA - m*m, 0.f);
        float sc = ga[t]*rsqrtf(v + 1e-5f);
        SSa[t] = sc;
        SSa[Ca+t] = fmaf(-m, sc, ba[t]);
    }
    int u = t - 256;
    if (u >= 0 && u < Cb) {
        float m = Sb[u]*invB;
        float v = fmaxf(Sb[Cb+u]*invB - m*m, 0.f);
        float sc = gb[u]*rsqrtf(v + 1e-5f);
        SSb[u] = sc;
        SSb[Cb+u] = fmaf(-m, sc, bb[u]);
    }
}

// ---------------- layer 0 edge MLP: stats pass ----------------
__global__ __launch_bounds__(256) void k_edge_stats(const float* __restrict__ xf,
                                                    const int* __restrict__ ei,
                                                    const float* __restrict__ W,
                                                    float* __restrict__ S) {
    __shared__ float w[256];
    __shared__ float red[64];
    int tid = threadIdx.x;
    w[tid] = W[tid];
    if (tid < 64) red[tid] = 0.f;
    __syncthreads();
    float s[32], q[32];
#pragma unroll
    for (int c = 0; c < 32; ++c) { s[c] = 0.f; q[c] = 0.f; }
    for (int e = blockIdx.x*256 + tid; e < EG; e += gridDim.x*256) {
        int b = e >> 17, j = e & (EE-1);
        const int* base = ei + (size_t)b*2*EE;
        int ctr = base[j], nbr = base[EE + j];
        const float4* pc = (const float4*)(xf + ((size_t)(b<<14) + ctr)*8);
        const float4* pn = (const float4*)(xf + ((size_t)(b<<14) + nbr)*8);
        float4 c0 = pc[0], c1 = pc[1], n0 = pn[0], n1 = pn[1];
        float d[8] = {n0.x-c0.x, n0.y-c0.y, n0.z-c0.z, n0.w-c0.w,
                      n1.x-c1.x, n1.y-c1.y, n1.z-c1.z, n1.w-c1.w};
#pragma unroll
        for (int c = 0; c < 32; ++c) {
            float z = 0.f;
#pragma unroll
            for (int k = 0; k < 8; ++k) z = fmaf(d[k], w[k*32+c], z);
            s[c] += z; q[c] = fmaf(z, z, q[c]);
        }
    }
#pragma unroll
    for (int off = 32; off >= 1; off >>= 1) {
#pragma unroll
        for (int c = 0; c < 32; ++c) {
            s[c] += __shfl_xor(s[c], off, 64);
            q[c] += __shfl_xor(q[c], off, 64);
        }
    }
    if ((tid & 63) == 0) {
#pragma unroll
        for (int c = 0; c < 32; ++c) { atomicAdd(&red[c], s[c]); atomicAdd(&red[32+c], q[c]); }
    }
    __syncthreads();
    if (tid < 64) atomicAdd(&S[tid], red[tid]);
}

// ---- layer 0 edge apply: BNa(x0raw)+lrelu + edge MLP max, write x0 final ----
__global__ __launch_bounds__(256) void k_edge_apply(const float* __restrict__ xf,
                                                    const int* __restrict__ ei,
                                                    const float* __restrict__ W,
                                                    const float* __restrict__ SSa,
                                                    const float* __restrict__ SSb,
                                                    float* __restrict__ x0) {
    __shared__ float w[256];
    __shared__ float scb[32], shb[32], sca[32], sha[32];
    int tid = threadIdx.x;
    w[tid] = W[tid];
    if (tid < 32) {
        scb[tid] = SSb[tid]; shb[tid] = SSb[32+tid];
        sca[tid] = SSa[tid]; sha[tid] = SSa[32+tid];
    }
    __syncthreads();
    int r = blockIdx.x*256 + tid;
    int b = r >> 14, n = r & (NN-1);
    const int* nb = ei + (size_t)b*2*EE + EE + n*KK;
    const float4* pc = (const float4*)(xf + (size_t)r*8);
    float4 c0 = pc[0], c1 = pc[1];
    float mx[32];
#pragma unroll
    for (int c = 0; c < 32; ++c) mx[c] = -3.0e38f;
    for (int k = 0; k < KK; ++k) {
        int j = nb[k];
        const float4* pn = (const float4*)(xf + ((size_t)(b<<14) + j)*8);
        float4 n0 = pn[0], n1 = pn[1];
        float d[8] = {n0.x-c0.x, n0.y-c0.y, n0.z-c0.z, n0.w-c0.w,
                      n1.x-c1.x, n1.y-c1.y, n1.z-c1.z, n1.w-c1.w};
#pragma unroll
        for (int c = 0; c < 32; ++c) {
            float z = 0.f;
#pragma unroll
            for (int k2 = 0; k2 < 8; ++k2) z = fmaf(d[k2], w[k2*32+c], z);
            float y = lrelu(fmaf(z, scb[c], shb[c]));
            mx[c] = fmaxf(mx[c], y);
        }
    }
    float4* xp = (float4*)(x0 + (size_t)r*32);
#pragma unroll
    for (int i = 0; i < 8; ++i) {
        float4 v = xp[i];
        v.x = lrelu(fmaf(v.x, sca[i*4+0], sha[i*4+0])) + mx[i*4+0];
        v.y = lrelu(fmaf(v.y, sca[i*4+1], sha[i*4+1])) + mx[i*4+1];
        v.z = lrelu(fmaf(v.z, sca[i*4+2], sha[i*4+2])) + mx[i*4+2];
        v.w = lrelu(fmaf(v.w, sca[i*4+3], sha[i*4+3])) + mx[i*4+3];
        xp[i] = v;
    }
}

// ---- weight prep: pack Wa|Wb into MFMA B-fragment order, hi/lo bf16 planes ----
// fragment f = nt*KT + kt; slot = (kq*16 + n) ^ (2*(f&3)); idx = f*512 + slot*8 + j
template<int CI, int CO>
__global__ __launch_bounds__(256) void k_packW(const float* __restrict__ Wa,
                                               const float* __restrict__ Wb,
                                               unsigned short* __restrict__ Wp) {
    constexpr int NT = 2*CO;
    constexpr int KT = CI/32;
    constexpr int WPLANE = NT*CI;
    int t = blockIdx.x*256 + threadIdx.x;
    if (t >= NT*CI) return;
    int ng = t % NT, k = t / NT;
    float v = (ng < CO) ? Wa[(size_t)k*CO + ng] : Wb[(size_t)k*CO + (ng - CO)];
    unsigned short hi = f2bf(v);
    unsigned short lo = f2bf(v - bf2f(hi));
    int nt = ng >> 4, n = ng & 15;
    int kt = k >> 5, kq = (k & 31) >> 3, j = k & 7;
    int f = nt*KT + kt;
    int idx = f*512 + (((kq*16 + n) ^ (2*(f&3)))<<3) + j;
    Wp[idx] = hi;
    Wp[WPLANE + idx] = lo;
}

// ---- fused dual MFMA GEMM: Za = X@Wa (fp32), Zb = X@Wb (bf16), + col stats ----
// split precision: X=Xhi+Xlo, W=Whi+Wlo; Z ~= Xhi*Whi + Xlo*Whi + Xhi*Wlo
template<int CI, int CO>
__global__ __launch_bounds__(256) void k_mfma_dual(const float* __restrict__ X,
                                                   const unsigned short* __restrict__ Wp,
                                                   float* __restrict__ Za,
                                                   unsigned short* __restrict__ Zb,
                                                   float* __restrict__ Sa,
                                                   float* __restrict__ Sb) {
    constexpr int NT = 2*CO;
    constexpr int KT = CI/32;
    constexpr int CHUNKS = NT/128;
    constexpr int PLANE = 128*CI;      // X LDS plane (ushorts)
    constexpr int WPLANE = NT*CI;
    __shared__ unsigned short Xs[2*PLANE];
    int tid = threadIdx.x;
    int lane = tid & 63, wid = tid >> 6;
    int wm = wid & 1, wn = wid >> 1;
    size_t rowbase = (size_t)blockIdx.x * 128;
    // ---- stage X (fp32 global, coalesced) -> hi/lo bf16 fragment-packed LDS ----
    constexpr int F4PR = CI/4;
    for (int u = tid; u < 128*F4PR; u += 256) {
        int r = u / F4PR, k0 = (u % F4PR)*4;
        float4 v = *(const float4*)&X[(rowbase + r)*CI + k0];
        int mt = r >> 4, m = r & 15;
        int kt = k0 >> 5, kq = (k0 & 31) >> 3, j0 = k0 & 7;
        int f = mt*KT + kt;
        int idx = f*512 + (((kq*16 + m) ^ (2*(f&3)))<<3) + j0;
        unsigned short h0 = f2bf(v.x), h1 = f2bf(v.y), h2 = f2bf(v.z), h3 = f2bf(v.w);
        ushort4 hv = {h0, h1, h2, h3};
        ushort4 lv = {f2bf(v.x - bf2f(h0)), f2bf(v.y - bf2f(h1)),
                      f2bf(v.z - bf2f(h2)), f2bf(v.w - bf2f(h3))};
        *(ushort4*)&Xs[idx] = hv;
        *(ushort4*)&Xs[PLANE + idx] = lv;
    }
    __syncthreads();
    for (int ch = 0; ch < CHUNKS; ++ch) {
        float4v acc[4][4];
#pragma unroll
        for (int i = 0; i < 4; ++i)
#pragma unroll
            for (int j = 0; j < 4; ++j)
                acc[i][j] = (float4v){0.f, 0.f, 0.f, 0.f};
#pragma unroll
        for (int kt = 0; kt < KT; ++kt) {
            short8v ah[4], al[4], wh[4], wl[4];
#pragma unroll
            for (int i = 0; i < 4; ++i) {
                int f = (wm*4 + i)*KT + kt;
                int off = f*512 + ((lane ^ (2*(f&3)))<<3);
                ah[i] = *(const short8v*)&Xs[off];
                al[i] = *(const short8v*)&Xs[PLANE + off];
            }
#pragma unroll
            for (int j = 0; j < 4; ++j) {
                int fw = (ch*8 + wn*4 + j)*KT + kt;
                int offw = fw*512 + ((lane ^ (2*(fw&3)))<<3);
                wh[j] = *(const short8v*)&Wp[offw];
                wl[j] = *(const short8v*)&Wp[WPLANE + offw];
            }
#pragma unroll
            for (int i = 0; i < 4; ++i)
#pragma unroll
                for (int j = 0; j < 4; ++j) {
                    acc[i][j] = __builtin_amdgcn_mfma_f32_16x16x32_bf16(ah[i], wh[j], acc[i][j], 0, 0, 0);
                    acc[i][j] = __builtin_amdgcn_mfma_f32_16x16x32_bf16(al[i], wh[j], acc[i][j], 0, 0, 0);
                    acc[i][j] = __builtin_amdgcn_mfma_f32_16x16x32_bf16(ah[i], wl[j], acc[i][j], 0, 0, 0);
                }
        }
        // ---- epilogue: store + stats per n-tile ----
#pragma unroll
        for (int j = 0; j < 4; ++j) {
            int ntg = ch*8 + wn*4 + j;
            int ngbase = ntg*16;
            bool isA = (ngbase < CO);
            int col = (isA ? ngbase : ngbase - CO) + (lane & 15);
            float s = 0.f, q = 0.f;
#pragma unroll
            for (int i = 0; i < 4; ++i) {
#pragma unroll
                for (int reg = 0; reg < 4; ++reg) {
                    float vv = acc[i][j][reg];
                    size_t row = rowbase + (size_t)(wm*64 + i*16 + ((lane>>4)<<2) + reg);
                    if (isA) Za[row*CO + col] = vv;
                    else     Zb[row*CO + col] = f2bf(vv);
                    s += vv; q = fmaf(vv, vv, q);
                }
            }
            s += __shfl_xor(s, 16, 64); q += __shfl_xor(q, 16, 64);
            s += __shfl_xor(s, 32, 64); q += __shfl_xor(q, 32, 64);
            if (lane < 16) {
                float* Sg = isA ? Sa : Sb;
                atomicAdd(&Sg[col], s);
                atomicAdd(&Sg[CO + col], q);
            }
        }
    }
}

// ---- fused: BNa+lrelu on center row, gather 8 nbrs from bf16 zb w/ BNb+lrelu, max, add ----
template<int CO>
__global__ __launch_bounds__(256) void k_gathermax(float* __restrict__ xi,
                                                   const unsigned short* __restrict__ zbh,
                                                   const int* __restrict__ ei,
                                                   const float* __restrict__ SSa,
                                                   const float* __restrict__ SSb) {
    constexpr int CQ = CO/8;
    int t = blockIdx.x*256 + threadIdx.x;
    int r = t / CQ;
    int c8 = (t % CQ)*8;
    int b = r >> 14, n = r & (NN-1);
    const int* nb = ei + (size_t)b*2*EE + EE + n*KK;
    float4 sb0 = *(const float4*)&SSb[c8],    sb1 = *(const float4*)&SSb[c8+4];
    float4 hb0 = *(const float4*)&SSb[CO+c8], hb1 = *(const float4*)&SSb[CO+c8+4];
    int nbr[KK];
#pragma unroll
    for (int k = 0; k < KK; ++k) nbr[k] = nb[k];
    size_t bbase = ((size_t)(b<<14))*CO + c8;
    float4 mx0 = make_float4(-3e38f,-3e38f,-3e38f,-3e38f), mx1 = mx0;
#pragma unroll
    for (int k = 0; k < KK; ++k) {
        const unsigned short* p = zbh + bbase + (size_t)nbr[k]*CO;
        ushort4 u0 = *(const ushort4*)p;
        ushort4 u1 = *(const ushort4*)(p+4);
        mx0.x = fmaxf(mx0.x, lrelu(fmaf(bf2f(u0.x), sb0.x, hb0.x)));
        mx0.y = fmaxf(mx0.y, lrelu(fmaf(bf2f(u0.y), sb0.y, hb0.y)));
        mx0.z = fmaxf(mx0.z, lrelu(fmaf(bf2f(u0.z), sb0.z, hb0.z)));
        mx0.w = fmaxf(mx0.w, lrelu(fmaf(bf2f(u0.w), sb0.w, hb0.w)));
        mx1.x = fmaxf(mx1.x, lrelu(fmaf(bf2f(u1.x), sb1.x, hb1.x)));
        mx1.y = fmaxf(mx1.y, lrelu(fmaf(bf2f(u1.y), sb1.y, hb1.y)));
        mx1.z = fmaxf(mx1.z, lrelu(fmaf(bf2f(u1.z), sb1.z, hb1.z)));
        mx1.w = fmaxf(mx1.w, lrelu(fmaf(bf2f(u1.w), sb1.w, hb1.w)));
    }
    float4 sa0 = *(const float4*)&SSa[c8],    sa1 = *(const float4*)&SSa[c8+4];
    float4 ha0 = *(const float4*)&SSa[CO+c8], ha1 = *(const float4*)&SSa[CO+c8+4];
    float4* xp0 = (float4*)&xi[(size_t)r*CO + c8];
    float4* xp1 = xp0 + 1;
    float4 a0 = *xp0, a1 = *xp1;
    a0.x = lrelu(fmaf(a0.x, sa0.x, ha0.x)) + mx0.x;
    a0.y = lrelu(fmaf(a0.y, sa0.y, ha0.y)) + mx0.y;
    a0.z = lrelu(fmaf(a0.z, sa0.z, ha0.z)) + mx0.z;
    a0.w = lrelu(fmaf(a0.w, sa0.w, ha0.w)) + mx0.w;
    a1.x = lrelu(fmaf(a1.x, sa1.x, ha1.x)) + mx1.x;
    a1.y = lrelu(fmaf(a1.y, sa1.y, ha1.y)) + mx1.y;
    a1.z = lrelu(fmaf(a1.z, sa1.z, ha1.z)) + mx1.z;
    a1.w = lrelu(fmaf(a1.w, sa1.w, ha1.w)) + mx1.w;
    *xp0 = a0;
    *xp1 = a1;
}

// ---------------- concat @ Wcat dot (one wave per row) ----------------
__global__ __launch_bounds__(256) void k_catdot(const float* __restrict__ x0,
                                                const float* __restrict__ x1,
                                                const float* __restrict__ x2,
                                                const float* __restrict__ x3,
                                                const float* __restrict__ Wc,
                                                float* __restrict__ zc) {
    int r = blockIdx.x*4 + (threadIdx.x >> 6);
    int l = threadIdx.x & 63;
    float s = 0.f;
    if (l < 32) s = x0[(size_t)r*32 + l]*Wc[l];
    s = fmaf(x1[(size_t)r*64 + l], Wc[32+l], s);
    s = fmaf(x2[(size_t)r*128 + l],      Wc[96+l],  s);
    s = fmaf(x2[(size_t)r*128 + 64 + l], Wc[160+l], s);
#pragma unroll
    for (int qd = 0; qd < 4; ++qd)
        s = fmaf(x3[(size_t)r*256 + qd*64 + l], Wc[224 + qd*64 + l], s);
#pragma unroll
    for (int off = 32; off >= 1; off >>= 1) s += __shfl_xor(s, off, 64);
    if (l == 0) zc[r] = s;
}

// ---------------- final: BN(1 col) + leaky + bias ----------------
__global__ __launch_bounds__(256) void k_catfinal(const float* __restrict__ zc,
                                                  const float* __restrict__ S,
                                                  const float* __restrict__ g,
                                                  const float* __restrict__ bb,
                                                  const float* __restrict__ bias,
                                                  float* __restrict__ out) {
    int r = blockIdx.x*256 + threadIdx.x;
    const float invR = 1.f/65536.f;
    float m = S[0]*invR;
    float v = fmaxf(S[1]*invR - m*m, 0.f);
    float sc = g[0]*rsqrtf(v + 1e-5f);
    float sh = fmaf(-m, sc, bb[0]);
    float y = lrelu(fmaf(zc[r], sc, sh));
    out[r] = y + bias[0];
}

extern "C" void kernel_launch(void* const* d_in, const int* in_sizes, int n_in,
                              void* d_out, int out_size, void* d_ws, size_t ws_size,
                              hipStream_t stream) {
    const float* x    = (const float*)d_in[0];
    const int*   ei   = (const int*)d_in[1];
    const float* W0a  = (const float*)d_in[2];
    const float* g0a  = (const float*)d_in[3];
    const float* b0a  = (const float*)d_in[4];
    const float* W0b  = (const float*)d_in[5];
    const float* g0b  = (const float*)d_in[6];
    const float* b0b  = (const float*)d_in[7];
    const float* W1a  = (const float*)d_in[8];
    const float* g1a  = (const float*)d_in[9];
    const float* b1a  = (const float*)d_in[10];
    const float* W1b  = (const float*)d_in[11];
    const float* g1b  = (const float*)d_in[12];
    const float* b1b  = (const float*)d_in[13];
    const float* W2a  = (const float*)d_in[14];
    const float* g2a  = (const float*)d_in[15];
    const float* b2a  = (const float*)d_in[16];
    const float* W2b  = (const float*)d_in[17];
    const float* g2b  = (const float*)d_in[18];
    const float* b2b  = (const float*)d_in[19];
    const float* W3a  = (const float*)d_in[20];
    const float* g3a  = (const float*)d_in[21];
    const float* b3a  = (const float*)d_in[22];
    const float* W3b  = (const float*)d_in[23];
    const float* g3b  = (const float*)d_in[24];
    const float* b3b  = (const float*)d_in[25];
    const float* Wcat = (const float*)d_in[26];
    const float* gcat = (const float*)d_in[27];
    const float* bcat = (const float*)d_in[28];
    const float* bias = (const float*)d_in[29];
    float* out = (float*)d_out;

    float* ws = (float*)d_ws;
    float* x0 = ws + OFF_X0;
    float* x1 = ws + OFF_X1;
    float* x2 = ws + OFF_X2;
    float* x3 = ws + OFF_X3;
    unsigned short* zbh = (unsigned short*)(ws + OFF_ZB);
    float* zc = ws + OFF_ZC;
    float* S  = ws + OFF_S;
    float* SS = ws + OFF_SS;
    unsigned short* wpbase = (unsigned short*)(ws + OFF_WP);
    unsigned short* wp1 = wpbase + WP1_OFF;
    unsigned short* wp2 = wpbase + WP2_OFF;
    unsigned short* wp3 = wpbase + WP3_OFF;
    auto Sl  = [&](int i) { return S  + i*512; };
    auto SSl = [&](int i) { return SS + i*512; };

    const float invR = 1.f/(float)RR;
    const float invE = 1.f/(float)EG;

    hipMemsetAsync(S, 0, 9*512*sizeof(float), stream);

    // ---- weight prep (tiny, independent) ----
    k_packW<32,64><<<(128*32+255)/256, 256, 0, stream>>>(W1a, W1b, wp1);
    k_packW<64,128><<<(256*64+255)/256, 256, 0, stream>>>(W2a, W2b, wp2);
    k_packW<128,256><<<(512*128+255)/256, 256, 0, stream>>>(W3a, W3b, wp3);

    // ---- layer 0 ----
    k_l0_node<<<RR/256, 256, 0, stream>>>(x, W0a, x0, Sl(0));
    k_edge_stats<<<256, 256, 0, stream>>>(x, ei, W0b, Sl(1));
    k_finalize2<<<1, 512, 0, stream>>>(Sl(0), g0a, b0a, invR, SSl(0), 32,
                                       Sl(1), g0b, b0b, invE, SSl(1), 32);
    k_edge_apply<<<RR/256, 256, 0, stream>>>(x, ei, W0b, SSl(0), SSl(1), x0);

    // ---- layer 1: 32 -> 64 ----
    k_mfma_dual<32,64><<<RR/128, 256, 0, stream>>>(x0, wp1, x1, zbh, Sl(2), Sl(3));
    k_finalize2<<<1, 512, 0, stream>>>(Sl(2), g1a, b1a, invR, SSl(2), 64,
                                       Sl(3), g1b, b1b, invR, SSl(3), 64);
    k_gathermax<64><<<RR*8/256, 256, 0, stream>>>(x1, zbh, ei, SSl(2), SSl(3));

    // ---- layer 2: 64 -> 128 ----
    k_mfma_dual<64,128><<<RR/128, 256, 0, stream>>>(x1, wp2, x2, zbh, Sl(4), Sl(5));
    k_finalize2<<<1, 512, 0, stream>>>(Sl(4), g2a, b2a, invR, SSl(4), 128,
                                       Sl(5), g2b, b2b, invR, SSl(5), 128);
    k_gathermax<128><<<RR*16/256, 256, 0, stream>>>(x2, zbh, ei, SSl(4), SSl(5));

    // ---- layer 3: 128 -> 256 ----
    k_mfma_dual<128,256><<<RR/128, 256, 0, stream>>>(x2, wp3, x3, zbh, Sl(6), Sl(7));
    k_finalize2<<<1, 512, 0, stream>>>(Sl(6), g3a, b3a, invR, SSl(6), 256,
                                       Sl(7), g3b, b3b, invR, SSl(7), 256);
    k_gathermax<256><<<RR*32/256, 256, 0, stream>>>(x3, zbh, ei, SSl(6), SSl(7));

    // ---- cat head ----
    k_catdot<<<RR/4, 256, 0, stream>>>(x0, x1, x2, x3, Wcat, zc);
    k_colstats<1><<<512, 256, 0, stream>>>(zc, RR, Sl(8));
    k_catfinal<<<RR/256, 256, 0, stream>>>(zc, Sl(8), gcat, bcat, bias, out);
}

// Round 4
// 465.501 us; speedup vs baseline: 1.7141x; 1.0379x over previous
//
#include <hip/hip_runtime.h>
#include <math.h>

// Problem constants
static constexpr int BB = 4;        // batch
static constexpr int NN = 16384;    // nodes per batch
static constexpr int KK = 8;        // neighbors per node
static constexpr int EE = 131072;   // edges per batch = NN*KK
static constexpr int RR = 65536;    // BB*NN rows
static constexpr int EG = 524288;   // BB*EE edges total

// Workspace layout (float offsets)
static constexpr size_t OFF_X0 = 0;                      // 65536*32 fp32
static constexpr size_t OFF_X1 = OFF_X0 + (size_t)RR*32; // 65536*64 fp32
static constexpr size_t OFF_X2 = OFF_X1 + (size_t)RR*64; // 65536*128 fp32
static constexpr size_t OFF_X3 = OFF_X2 + (size_t)RR*128;// 65536*256 fp32
static constexpr size_t OFF_ZB = OFF_X3 + (size_t)RR*256;// 65536*256 *fp16* (b-branch)
static constexpr size_t OFF_ZC = OFF_ZB + (size_t)RR*128;// 65536 fp32
static constexpr size_t OFF_S  = OFF_ZC + (size_t)RR;    // 9 slots * 512
static constexpr size_t OFF_SS = OFF_S + 9*512;          // 9 slots * 512
static constexpr size_t OFF_WP = OFF_SS + 9*512;         // packed fp16 weights (ushort)
// packed weight offsets in ushorts relative to OFF_WP*2:
static constexpr size_t WP1_OFF = 0;               // 128*32   = 4096
static constexpr size_t WP2_OFF = 4096;            // 256*64   = 16384
static constexpr size_t WP3_OFF = 4096 + 16384;    // 512*128  = 65536

__device__ __forceinline__ float lrelu(float x) { return fmaxf(x, 0.2f*x); }

__device__ __forceinline__ unsigned short f2h(float f) {
    _Float16 h = (_Float16)f;   // v_cvt_f16_f32, RTN
    return *(unsigned short*)&h;
}
__device__ __forceinline__ float h2f(unsigned short u) {
    _Float16 h = *(_Float16*)&u;
    return (float)h;
}

typedef __attribute__((ext_vector_type(8))) _Float16 half8v;
typedef __attribute__((ext_vector_type(4))) float float4v;

// ---------------- layer 0: node GEMM 8->32 (pre-BN) + fused col stats ----------------
__global__ __launch_bounds__(256) void k_l0_node(const float* __restrict__ xf,
                                                 const float* __restrict__ W,
                                                 float* __restrict__ z,
                                                 float* __restrict__ S) {
    __shared__ float w[256];
    __shared__ float red[64];
    int tid = threadIdx.x;
    w[tid] = W[tid];
    if (tid < 64) red[tid] = 0.f;
    __syncthreads();
    int r = blockIdx.x*256 + tid;
    const float4* xr = (const float4*)(xf + (size_t)r*8);
    float4 a = xr[0], b = xr[1];
    float xv[8] = {a.x,a.y,a.z,a.w,b.x,b.y,b.z,b.w};
    float op[32];
#pragma unroll
    for (int c = 0; c < 32; ++c) {
        float s = 0.f;
#pragma unroll
        for (int k = 0; k < 8; ++k) s = fmaf(xv[k], w[k*32+c], s);
        op[c] = s;
    }
    float4* zp = (float4*)(z + (size_t)r*32);
#pragma unroll
    for (int i = 0; i < 8; ++i)
        zp[i] = make_float4(op[i*4], op[i*4+1], op[i*4+2], op[i*4+3]);
#pragma unroll
    for (int c = 0; c < 32; ++c) {
        float s = op[c], q = op[c]*op[c];
#pragma unroll
        for (int off = 32; off >= 1; off >>= 1) {
            s += __shfl_xor(s, off, 64);
            q += __shfl_xor(q, off, 64);
        }
        if ((tid & 63) == 0) { atomicAdd(&red[c], s); atomicAdd(&red[32+c], q); }
    }
    __syncthreads();
    if (tid < 64) atomicAdd(&S[tid], red[tid]);
}

// ---------------- column stats (only for the 1-col cat head) ----------------
template<int C>
__global__ __launch_bounds__(256) void k_colstats(const float* __restrict__ Z, int R,
                                                  float* __restrict__ S) {
    constexpr int TPC = 256 / C;
    __shared__ float ls[256];
    __shared__ float lq[256];
    int tid = threadIdx.x;
    int c = tid % C, rr = tid / C;
    float s = 0.f, q = 0.f;
    for (int r = blockIdx.x*TPC + rr; r < R; r += gridDim.x*TPC) {
        float v = Z[(size_t)r*C + c];
        s += v; q = fmaf(v, v, q);
    }
    ls[tid] = s; lq[tid] = q;
    __syncthreads();
#pragma unroll
    for (int half = TPC/2; half >= 1; half >>= 1) {
        if (rr < half) { ls[tid] += ls[tid + half*C]; lq[tid] += lq[tid + half*C]; }
        __syncthreads();
    }
    if (rr == 0) { atomicAdd(&S[c], ls[tid]); atomicAdd(&S[C+c], lq[tid]); }
}

// ---------------- finalize (two BN slots in one launch) ----------------
__global__ void k_finalize2(const float* __restrict__ Sa, const float* __restrict__ ga,
                            const float* __restrict__ ba, float invA,
                            float* __restrict__ SSa, int Ca,
                            const float* __restrict__ Sb, const float* __restrict__ gb,
                            const float* __restrict__ bb, float invB,
                            float* __restrict__ SSb, int Cb) {
    int t = threadIdx.x;
    if (t < Ca) {
        float m = Sa[t]*invA;
        float v = fmaxf(Sa[Ca+t]*invA - m*m, 0.f);
        float sc = ga[t]*rsqrtf(v + 1e-5f);
        SSa[t] = sc;
        SSa[Ca+t] = fmaf(-m, sc, ba[t]);
    }
    int u = t - 256;
    if (u >= 0 && u < Cb) {
        float m = Sb[u]*invB;
        float v = fmaxf(Sb[Cb+u]*invB - m*m, 0.f);
        float sc = gb[u]*rsqrtf(v + 1e-5f);
        SSb[u] = sc;
        SSb[Cb+u] = fmaf(-m, sc, bb[u]);
    }
}

// ---------------- layer 0 edge MLP: stats pass ----------------
__global__ __launch_bounds__(256) void k_edge_stats(const float* __restrict__ xf,
                                                    const int* __restrict__ ei,
                                                    const float* __restrict__ W,
                                                    float* __restrict__ S) {
    __shared__ float w[256];
    __shared__ float red[64];
    int tid = threadIdx.x;
    w[tid] = W[tid];
    if (tid < 64) red[tid] = 0.f;
    __syncthreads();
    float s[32], q[32];
#pragma unroll
    for (int c = 0; c < 32; ++c) { s[c] = 0.f; q[c] = 0.f; }
    for (int e = blockIdx.x*256 + tid; e < EG; e += gridDim.x*256) {
        int b = e >> 17, j = e & (EE-1);
        const int* base = ei + (size_t)b*2*EE;
        int ctr = base[j], nbr = base[EE + j];
        const float4* pc = (const float4*)(xf + ((size_t)(b<<14) + ctr)*8);
        const float4* pn = (const float4*)(xf + ((size_t)(b<<14) + nbr)*8);
        float4 c0 = pc[0], c1 = pc[1], n0 = pn[0], n1 = pn[1];
        float d[8] = {n0.x-c0.x, n0.y-c0.y, n0.z-c0.z, n0.w-c0.w,
                      n1.x-c1.x, n1.y-c1.y, n1.z-c1.z, n1.w-c1.w};
#pragma unroll
        for (int c = 0; c < 32; ++c) {
            float z = 0.f;
#pragma unroll
            for (int k = 0; k < 8; ++k) z = fmaf(d[k], w[k*32+c], z);
            s[c] += z; q[c] = fmaf(z, z, q[c]);
        }
    }
#pragma unroll
    for (int off = 32; off >= 1; off >>= 1) {
#pragma unroll
        for (int c = 0; c < 32; ++c) {
            s[c] += __shfl_xor(s[c], off, 64);
            q[c] += __shfl_xor(q[c], off, 64);
        }
    }
    if ((tid & 63) == 0) {
#pragma unroll
        for (int c = 0; c < 32; ++c) { atomicAdd(&red[c], s[c]); atomicAdd(&red[32+c], q[c]); }
    }
    __syncthreads();
    if (tid < 64) atomicAdd(&S[tid], red[tid]);
}

// ---- layer 0 edge apply: BNa(x0raw)+lrelu + edge MLP max, write x0 final ----
__global__ __launch_bounds__(256) void k_edge_apply(const float* __restrict__ xf,
                                                    const int* __restrict__ ei,
                                                    const float* __restrict__ W,
                                                    const float* __restrict__ SSa,
                                                    const float* __restrict__ SSb,
                                                    float* __restrict__ x0) {
    __shared__ float w[256];
    __shared__ float scb[32], shb[32], sca[32], sha[32];
    int tid = threadIdx.x;
    w[tid] = W[tid];
    if (tid < 32) {
        scb[tid] = SSb[tid]; shb[tid] = SSb[32+tid];
        sca[tid] = SSa[tid]; sha[tid] = SSa[32+tid];
    }
    __syncthreads();
    int r = blockIdx.x*256 + tid;
    int b = r >> 14, n = r & (NN-1);
    const int* nb = ei + (size_t)b*2*EE + EE + n*KK;
    const float4* pc = (const float4*)(xf + (size_t)r*8);
    float4 c0 = pc[0], c1 = pc[1];
    float mx[32];
#pragma unroll
    for (int c = 0; c < 32; ++c) mx[c] = -3.0e38f;
    for (int k = 0; k < KK; ++k) {
        int j = nb[k];
        const float4* pn = (const float4*)(xf + ((size_t)(b<<14) + j)*8);
        float4 n0 = pn[0], n1 = pn[1];
        float d[8] = {n0.x-c0.x, n0.y-c0.y, n0.z-c0.z, n0.w-c0.w,
                      n1.x-c1.x, n1.y-c1.y, n1.z-c1.z, n1.w-c1.w};
#pragma unroll
        for (int c = 0; c < 32; ++c) {
            float z = 0.f;
#pragma unroll
            for (int k2 = 0; k2 < 8; ++k2) z = fmaf(d[k2], w[k2*32+c], z);
            float y = lrelu(fmaf(z, scb[c], shb[c]));
            mx[c] = fmaxf(mx[c], y);
        }
    }
    float4* xp = (float4*)(x0 + (size_t)r*32);
#pragma unroll
    for (int i = 0; i < 8; ++i) {
        float4 v = xp[i];
        v.x = lrelu(fmaf(v.x, sca[i*4+0], sha[i*4+0])) + mx[i*4+0];
        v.y = lrelu(fmaf(v.y, sca[i*4+1], sha[i*4+1])) + mx[i*4+1];
        v.z = lrelu(fmaf(v.z, sca[i*4+2], sha[i*4+2])) + mx[i*4+2];
        v.w = lrelu(fmaf(v.w, sca[i*4+3], sha[i*4+3])) + mx[i*4+3];
        xp[i] = v;
    }
}

// ---- weight prep: pack Wa|Wb into MFMA B-fragment order, single fp16 plane ----
// fragment f = nt*KT + kt; slot = (kq*16 + n) ^ (2*(f&3)); idx = f*512 + slot*8 + j
template<int CI, int CO>
__global__ __launch_bounds__(256) void k_packW(const float* __restrict__ Wa,
                                               const float* __restrict__ Wb,
                                               unsigned short* __restrict__ Wp) {
    constexpr int NT = 2*CO;
    constexpr int KT = CI/32;
    int t = blockIdx.x*256 + threadIdx.x;
    if (t >= NT*CI) return;
    int ng = t % NT, k = t / NT;
    float v = (ng < CO) ? Wa[(size_t)k*CO + ng] : Wb[(size_t)k*CO + (ng - CO)];
    int nt = ng >> 4, n = ng & 15;
    int kt = k >> 5, kq = (k & 31) >> 3, j = k & 7;
    int f = nt*KT + kt;
    int idx = f*512 + (((kq*16 + n) ^ (2*(f&3)))<<3) + j;
    Wp[idx] = f2h(v);
}

// ---- fused dual MFMA GEMM (fp16): Za = X@Wa (fp32 out), Zb = X@Wb (fp16 out), + stats ----
template<int CI, int CO>
__global__ __launch_bounds__(256) void k_mfma_dual(const float* __restrict__ X,
                                                   const unsigned short* __restrict__ Wp,
                                                   float* __restrict__ Za,
                                                   unsigned short* __restrict__ Zb,
                                                   float* __restrict__ Sa,
                                                   float* __restrict__ Sb) {
    constexpr int NT = 2*CO;
    constexpr int KT = CI/32;
    constexpr int CHUNKS = NT/128;
    constexpr int PLANE = 128*CI;      // single fp16 X plane (ushorts)
    __shared__ unsigned short Xs[PLANE];
    int tid = threadIdx.x;
    int lane = tid & 63, wid = tid >> 6;
    int wm = wid & 1, wn = wid >> 1;
    size_t rowbase = (size_t)blockIdx.x * 128;
    // ---- stage X (fp32 global, coalesced) -> fp16 fragment-packed LDS ----
    constexpr int F4PR = CI/4;
    for (int u = tid; u < 128*F4PR; u += 256) {
        int r = u / F4PR, k0 = (u % F4PR)*4;
        float4 v = *(const float4*)&X[(rowbase + r)*CI + k0];
        int mt = r >> 4, m = r & 15;
        int kt = k0 >> 5, kq = (k0 & 31) >> 3, j0 = k0 & 7;
        int f = mt*KT + kt;
        int idx = f*512 + (((kq*16 + m) ^ (2*(f&3)))<<3) + j0;
        ushort4 hv = {f2h(v.x), f2h(v.y), f2h(v.z), f2h(v.w)};
        *(ushort4*)&Xs[idx] = hv;
    }
    __syncthreads();
    for (int ch = 0; ch < CHUNKS; ++ch) {
        float4v acc[4][4];
#pragma unroll
        for (int i = 0; i < 4; ++i)
#pragma unroll
            for (int j = 0; j < 4; ++j)
                acc[i][j] = (float4v){0.f, 0.f, 0.f, 0.f};
#pragma unroll
        for (int kt = 0; kt < KT; ++kt) {
            half8v ah[4], wv[4];
#pragma unroll
            for (int i = 0; i < 4; ++i) {
                int f = (wm*4 + i)*KT + kt;
                int off = f*512 + ((lane ^ (2*(f&3)))<<3);
                ah[i] = *(const half8v*)&Xs[off];
            }
#pragma unroll
            for (int j = 0; j < 4; ++j) {
                int fw = (ch*8 + wn*4 + j)*KT + kt;
                int offw = fw*512 + ((lane ^ (2*(fw&3)))<<3);
                wv[j] = *(const half8v*)&Wp[offw];
            }
#pragma unroll
            for (int i = 0; i < 4; ++i)
#pragma unroll
                for (int j = 0; j < 4; ++j)
                    acc[i][j] = __builtin_amdgcn_mfma_f32_16x16x32_f16(ah[i], wv[j], acc[i][j], 0, 0, 0);
        }
        // ---- epilogue: store + stats per n-tile ----
#pragma unroll
        for (int j = 0; j < 4; ++j) {
            int ntg = ch*8 + wn*4 + j;
            int ngbase = ntg*16;
            bool isA = (ngbase < CO);
            int col = (isA ? ngbase : ngbase - CO) + (lane & 15);
            float s = 0.f, q = 0.f;
#pragma unroll
            for (int i = 0; i < 4; ++i) {
#pragma unroll
                for (int reg = 0; reg < 4; ++reg) {
                    float vv = acc[i][j][reg];
                    size_t row = rowbase + (size_t)(wm*64 + i*16 + ((lane>>4)<<2) + reg);
                    if (isA) Za[row*CO + col] = vv;
                    else     Zb[row*CO + col] = f2h(vv);
                    s += vv; q = fmaf(vv, vv, q);
                }
            }
            s += __shfl_xor(s, 16, 64); q += __shfl_xor(q, 16, 64);
            s += __shfl_xor(s, 32, 64); q += __shfl_xor(q, 32, 64);
            if (lane < 16) {
                float* Sg = isA ? Sa : Sb;
                atomicAdd(&Sg[col], s);
                atomicAdd(&Sg[CO + col], q);
            }
        }
    }
}

// ---- fused: BNa+lrelu on center row, gather 8 nbrs from fp16 zb w/ BNb+lrelu, max, add ----
template<int CO>
__global__ __launch_bounds__(256) void k_gathermax(float* __restrict__ xi,
                                                   const unsigned short* __restrict__ zbh,
                                                   const int* __restrict__ ei,
                                                   const float* __restrict__ SSa,
                                                   const float* __restrict__ SSb) {
    constexpr int CQ = CO/8;
    int t = blockIdx.x*256 + threadIdx.x;
    int r = t / CQ;
    int c8 = (t % CQ)*8;
    int b = r >> 14, n = r & (NN-1);
    const int* nb = ei + (size_t)b*2*EE + EE + n*KK;
    float4 sb0 = *(const float4*)&SSb[c8],    sb1 = *(const float4*)&SSb[c8+4];
    float4 hb0 = *(const float4*)&SSb[CO+c8], hb1 = *(const float4*)&SSb[CO+c8+4];
    int nbr[KK];
#pragma unroll
    for (int k = 0; k < KK; ++k) nbr[k] = nb[k];
    size_t bbase = ((size_t)(b<<14))*CO + c8;
    float4 mx0 = make_float4(-3e38f,-3e38f,-3e38f,-3e38f), mx1 = mx0;
#pragma unroll
    for (int k = 0; k < KK; ++k) {
        const unsigned short* p = zbh + bbase + (size_t)nbr[k]*CO;
        ushort4 u0 = *(const ushort4*)p;
        ushort4 u1 = *(const ushort4*)(p+4);
        mx0.x = fmaxf(mx0.x, lrelu(fmaf(h2f(u0.x), sb0.x, hb0.x)));
        mx0.y = fmaxf(mx0.y, lrelu(fmaf(h2f(u0.y), sb0.y, hb0.y)));
        mx0.z = fmaxf(mx0.z, lrelu(fmaf(h2f(u0.z), sb0.z, hb0.z)));
        mx0.w = fmaxf(mx0.w, lrelu(fmaf(h2f(u0.w), sb0.w, hb0.w)));
        mx1.x = fmaxf(mx1.x, lrelu(fmaf(h2f(u1.x), sb1.x, hb1.x)));
        mx1.y = fmaxf(mx1.y, lrelu(fmaf(h2f(u1.y), sb1.y, hb1.y)));
        mx1.z = fmaxf(mx1.z, lrelu(fmaf(h2f(u1.z), sb1.z, hb1.z)));
        mx1.w = fmaxf(mx1.w, lrelu(fmaf(h2f(u1.w), sb1.w, hb1.w)));
    }
    float4 sa0 = *(const float4*)&SSa[c8],    sa1 = *(const float4*)&SSa[c8+4];
    float4 ha0 = *(const float4*)&SSa[CO+c8], ha1 = *(const float4*)&SSa[CO+c8+4];
    float4* xp0 = (float4*)&xi[(size_t)r*CO + c8];
    float4* xp1 = xp0 + 1;
    float4 a0 = *xp0, a1 = *xp1;
    a0.x = lrelu(fmaf(a0.x, sa0.x, ha0.x)) + mx0.x;
    a0.y = lrelu(fmaf(a0.y, sa0.y, ha0.y)) + mx0.y;
    a0.z = lrelu(fmaf(a0.z, sa0.z, ha0.z)) + mx0.z;
    a0.w = lrelu(fmaf(a0.w, sa0.w, ha0.w)) + mx0.w;
    a1.x = lrelu(fmaf(a1.x, sa1.x, ha1.x)) + mx1.x;
    a1.y = lrelu(fmaf(a1.y, sa1.y, ha1.y)) + mx1.y;
    a1.z = lrelu(fmaf(a1.z, sa1.z, ha1.z)) + mx1.z;
    a1.w = lrelu(fmaf(a1.w, sa1.w, ha1.w)) + mx1.w;
    *xp0 = a0;
    *xp1 = a1;
}

// ---------------- concat @ Wcat dot (one wave per row) ----------------
__global__ __launch_bounds__(256) void k_catdot(const float* __restrict__ x0,
                                                const float* __restrict__ x1,
                                                const float* __restrict__ x2,
                                                const float* __restrict__ x3,
                                                const float* __restrict__ Wc,
                                                float* __restrict__ zc) {
    int r = blockIdx.x*4 + (threadIdx.x >> 6);
    int l = threadIdx.x & 63;
    float s = 0.f;
    if (l < 32) s = x0[(size_t)r*32 + l]*Wc[l];
    s = fmaf(x1[(size_t)r*64 + l], Wc[32+l], s);
    s = fmaf(x2[(size_t)r*128 + l],      Wc[96+l],  s);
    s = fmaf(x2[(size_t)r*128 + 64 + l], Wc[160+l], s);
#pragma unroll
    for (int qd = 0; qd < 4; ++qd)
        s = fmaf(x3[(size_t)r*256 + qd*64 + l], Wc[224 + qd*64 + l], s);
#pragma unroll
    for (int off = 32; off >= 1; off >>= 1) s += __shfl_xor(s, off, 64);
    if (l == 0) zc[r] = s;
}

// ---------------- final: BN(1 col) + leaky + bias ----------------
__global__ __launch_bounds__(256) void k_catfinal(const float* __restrict__ zc,
                                                  const float* __restrict__ S,
                                                  const float* __restrict__ g,
                                                  const float* __restrict__ bb,
                                                  const float* __restrict__ bias,
                                                  float* __restrict__ out) {
    int r = blockIdx.x*256 + threadIdx.x;
    const float invR = 1.f/65536.f;
    float m = S[0]*invR;
    float v = fmaxf(S[1]*invR - m*m, 0.f);
    float sc = g[0]*rsqrtf(v + 1e-5f);
    float sh = fmaf(-m, sc, bb[0]);
    float y = lrelu(fmaf(zc[r], sc, sh));
    out[r] = y + bias[0];
}

extern "C" void kernel_launch(void* const* d_in, const int* in_sizes, int n_in,
                              void* d_out, int out_size, void* d_ws, size_t ws_size,
                              hipStream_t stream) {
    const float* x    = (const float*)d_in[0];
    const int*   ei   = (const int*)d_in[1];
    const float* W0a  = (const float*)d_in[2];
    const float* g0a  = (const float*)d_in[3];
    const float* b0a  = (const float*)d_in[4];
    const float* W0b  = (const float*)d_in[5];
    const float* g0b  = (const float*)d_in[6];
    const float* b0b  = (const float*)d_in[7];
    const float* W1a  = (const float*)d_in[8];
    const float* g1a  = (const float*)d_in[9];
    const float* b1a  = (const float*)d_in[10];
    const float* W1b  = (const float*)d_in[11];
    const float* g1b  = (const float*)d_in[12];
    const float* b1b  = (const float*)d_in[13];
    const float* W2a  = (const float*)d_in[14];
    const float* g2a  = (const float*)d_in[15];
    const float* b2a  = (const float*)d_in[16];
    const float* W2b  = (const float*)d_in[17];
    const float* g2b  = (const float*)d_in[18];
    const float* b2b  = (const float*)d_in[19];
    const float* W3a  = (const float*)d_in[20];
    const float* g3a  = (const float*)d_in[21];
    const float* b3a  = (const float*)d_in[22];
    const float* W3b  = (const float*)d_in[23];
    const float* g3b  = (const float*)d_in[24];
    const float* b3b  = (const float*)d_in[25];
    const float* Wcat = (const float*)d_in[26];
    const float* gcat = (const float*)d_in[27];
    const float* bcat = (const float*)d_in[28];
    const float* bias = (const float*)d_in[29];
    float* out = (float*)d_out;

    float* ws = (float*)d_ws;
    float* x0 = ws + OFF_X0;
    float* x1 = ws + OFF_X1;
    float* x2 = ws + OFF_X2;
    float* x3 = ws + OFF_X3;
    unsigned short* zbh = (unsigned short*)(ws + OFF_ZB);
    float* zc = ws + OFF_ZC;
    float* S  = ws + OFF_S;
    float* SS = ws + OFF_SS;
    unsigned short* wpbase = (unsigned short*)(ws + OFF_WP);
    unsigned short* wp1 = wpbase + WP1_OFF;
    unsigned short* wp2 = wpbase + WP2_OFF;
    unsigned short* wp3 = wpbase + WP3_OFF;
    auto Sl  = [&](int i) { return S  + i*512; };
    auto SSl = [&](int i) { return SS + i*512; };

    const float invR = 1.f/(float)RR;
    const float invE = 1.f/(float)EG;

    hipMemsetAsync(S, 0, 9*512*sizeof(float), stream);

    // ---- weight prep (tiny, independent) ----
    k_packW<32,64><<<(128*32+255)/256, 256, 0, stream>>>(W1a, W1b, wp1);
    k_packW<64,128><<<(256*64+255)/256, 256, 0, stream>>>(W2a, W2b, wp2);
    k_packW<128,256><<<(512*128+255)/256, 256, 0, stream>>>(W3a, W3b, wp3);

    // ---- layer 0 ----
    k_l0_node<<<RR/256, 256, 0, stream>>>(x, W0a, x0, Sl(0));
    k_edge_stats<<<256, 256, 0, stream>>>(x, ei, W0b, Sl(1));
    k_finalize2<<<1, 512, 0, stream>>>(Sl(0), g0a, b0a, invR, SSl(0), 32,
                                       Sl(1), g0b, b0b, invE, SSl(1), 32);
    k_edge_apply<<<RR/256, 256, 0, stream>>>(x, ei, W0b, SSl(0), SSl(1), x0);

    // ---- layer 1: 32 -> 64 ----
    k_mfma_dual<32,64><<<RR/128, 256, 0, stream>>>(x0, wp1, x1, zbh, Sl(2), Sl(3));
    k_finalize2<<<1, 512, 0, stream>>>(Sl(2), g1a, b1a, invR, SSl(2), 64,
                                       Sl(3), g1b, b1b, invR, SSl(3), 64);
    k_gathermax<64><<<RR*8/256, 256, 0, stream>>>(x1, zbh, ei, SSl(2), SSl(3));

    // ---- layer 2: 64 -> 128 ----
    k_mfma_dual<64,128><<<RR/128, 256, 0, stream>>>(x1, wp2, x2, zbh, Sl(4), Sl(5));
    k_finalize2<<<1, 512, 0, stream>>>(Sl(4), g2a, b2a, invR, SSl(4), 128,
                                       Sl(5), g2b, b2b, invR, SSl(5), 128);
    k_gathermax<128><<<RR*16/256, 256, 0, stream>>>(x2, zbh, ei, SSl(4), SSl(5));

    // ---- layer 3: 128 -> 256 ----
    k_mfma_dual<128,256><<<RR/128, 256, 0, stream>>>(x2, wp3, x3, zbh, Sl(6), Sl(7));
    k_finalize2<<<1, 512, 0, stream>>>(Sl(6), g3a, b3a, invR, SSl(6), 256,
                                       Sl(7), g3b, b3b, invR, SSl(7), 256);
    k_gathermax<256><<<RR*32/256, 256, 0, stream>>>(x3, zbh, ei, SSl(6), SSl(7));

    // ---- cat head ----
    k_catdot<<<RR/4, 256, 0, stream>>>(x0, x1, x2, x3, Wcat, zc);
    k_colstats<1><<<512, 256, 0, stream>>>(zc, RR, Sl(8));
    k_catfinal<<<RR/256, 256, 0, stream>>>(zc, Sl(8), gcat, bcat, bias, out);
}